// Round 16
// baseline (363.395 us; speedup 1.0000x reference)
//
#include <hip/hip_runtime.h>
#include <hip/hip_bf16.h>

typedef short bf16x8 __attribute__((ext_vector_type(8)));
typedef float f32x4 __attribute__((ext_vector_type(4)));
typedef unsigned short u16;
typedef unsigned int u32;

// dims (fixed per problem)
#define TSEQ 4096
#define DMODEL 1024
#define NHEAD 16
#define DHEAD 64
#define DFF 4096

__device__ __forceinline__ u16 f2bf(float f) {
    u32 u = __builtin_bit_cast(u32, f);
    u32 lsb = (u >> 16) & 1u;
    u += 0x7fffu + lsb;
    return (u16)(u >> 16);
}

__device__ __forceinline__ float exp2_hw(float x) {   // 2^x
    float r;
    asm("v_exp_f32 %0, %1" : "=v"(r) : "v"(x));
    return r;
}

__device__ __forceinline__ float rcp_hw(float x) {    // 1/x (approx, ~1ulp)
    float r;
    asm("v_rcp_f32 %0, %1" : "=v"(r) : "v"(x));
    return r;
}

__device__ __forceinline__ u32 cvt_pk_bf16(float a, float b) {  // lo=bf16(a), hi=bf16(b)
    u32 r;
    asm("v_cvt_pk_bf16_f32 %0, %1, %2" : "=v"(r) : "v"(a), "v"(b));
    return r;
}

__device__ __forceinline__ void gload_lds16(const u16* g, u16* l) {
    __builtin_amdgcn_global_load_lds(
        (const __attribute__((address_space(1))) u32*)g,
        (__attribute__((address_space(3))) u32*)l, 16, 0, 0);
}

// ---------------- fused prep: 4x weight transpose+cast AND ln1, one launch ----------
__device__ __forceinline__ void transpose_tile(
    const float* __restrict__ W, u16* __restrict__ Wt, int K, int N, int bx, int by,
    float (*tile)[65])
{
    const int t = threadIdx.x;
    const int c = t & 63, r4 = t >> 6;
    const int col0 = bx * 64;  // N dim
    const int row0 = by * 64;  // K dim
#pragma unroll
    for (int p = 0; p < 16; p++) {
        const int r = 4 * p + r4;
        tile[r][c] = W[(size_t)(row0 + r) * N + col0 + c];
    }
    __syncthreads();
#pragma unroll
    for (int p = 0; p < 16; p++) {
        const int r = 4 * p + r4;
        Wt[(size_t)(col0 + r) * K + row0 + c] = f2bf(tile[c][r]);
    }
}

__device__ __forceinline__ void ln_rows(
    const float* __restrict__ x, const float* __restrict__ sc,
    const float* __restrict__ bi, u16* __restrict__ out, int blk)
{
    const int lane = threadIdx.x & 63;
    const int row = blk * 4 + (threadIdx.x >> 6);
    const float* xr = x + (size_t)row * DMODEL;
    float4 v[4];
    float s = 0.f, s2 = 0.f;
#pragma unroll
    for (int q = 0; q < 4; q++) {
        v[q] = *(const float4*)(xr + 4 * (lane + 64 * q));
        s  += v[q].x + v[q].y + v[q].z + v[q].w;
        s2 += v[q].x * v[q].x + v[q].y * v[q].y + v[q].z * v[q].z + v[q].w * v[q].w;
    }
#pragma unroll
    for (int off = 1; off < 64; off <<= 1) {
        s  += __shfl_xor(s, off);
        s2 += __shfl_xor(s2, off);
    }
    const float mu = s * (1.f / DMODEL);
    const float rstd = rsqrtf(s2 * (1.f / DMODEL) - mu * mu + 1e-5f);
#pragma unroll
    for (int q = 0; q < 4; q++) {
        const int c = 4 * (lane + 64 * q);
        const float4 scv = *(const float4*)(sc + c);
        const float4 biv = *(const float4*)(bi + c);
        ushort4 ov;
        ov.x = f2bf((v[q].x - mu) * rstd * scv.x + biv.x);
        ov.y = f2bf((v[q].y - mu) * rstd * scv.y + biv.y);
        ov.z = f2bf((v[q].z - mu) * rstd * scv.z + biv.z);
        ov.w = f2bf((v[q].w - mu) * rstd * scv.w + biv.w);
        *(ushort4*)(out + (size_t)row * DMODEL + c) = ov;
    }
}

__global__ __launch_bounds__(256)
void prep_kernel(const float* __restrict__ x, const float* __restrict__ ln1_s,
                 const float* __restrict__ ln1_b, u16* __restrict__ h,
                 const float* __restrict__ W_attn, u16* __restrict__ WtAttn,
                 const float* __restrict__ W_proj, u16* __restrict__ WtProj,
                 const float* __restrict__ W_fc,   u16* __restrict__ WtFc,
                 const float* __restrict__ W_fc2,  u16* __restrict__ WtFc2)
{
    __shared__ float tile[64][65];
    int b = blockIdx.x;
    if (b < 1024) { ln_rows(x, ln1_s, ln1_b, h, b); return; }
    b -= 1024;
    if (b < 768)  { transpose_tile(W_attn, WtAttn, 1024, 3072, b % 48, b / 48, tile); return; }
    b -= 768;
    if (b < 256)  { transpose_tile(W_proj, WtProj, 1024, 1024, b % 16, b / 16, tile); return; }
    b -= 256;
    if (b < 1024) { transpose_tile(W_fc,   WtFc,   1024, 4096, b % 64, b / 64, tile); return; }
    b -= 1024;
    transpose_tile(W_fc2, WtFc2, 4096, 1024, b % 16, b / 16, tile);
}

// ---------------- V transpose: qkv bf16 [T,3072] V-part -> Vt[h][d][T] bf16 ----------
__global__ __launch_bounds__(256)
void v_transpose_kernel(const u16* __restrict__ qkv, u16* __restrict__ Vtg)
{
    __shared__ u16 tile[64][72];
    const int t = threadIdx.x;
    const int hh = blockIdx.y, t0 = blockIdx.x * 64;
#pragma unroll
    for (int p = 0; p < 2; p++) {
        const int L = p * 2048 + t * 8;
        const int r = L >> 6, c = L & 63;
        const bf16x8 v = *(const bf16x8*)(qkv + (size_t)(t0 + r) * 3072 + 2048 + hh * 64 + c);
#pragma unroll
        for (int i = 0; i < 8; i++) tile[c + i][r] = (u16)v[i];
    }
    __syncthreads();
#pragma unroll
    for (int p = 0; p < 2; p++) {
        const int L = p * 2048 + t * 8;
        const int d = L >> 6, c = L & 63;
        bf16x8 v;
#pragma unroll
        for (int i = 0; i < 8; i++) v[i] = (short)tile[d][c + i];
        *(bf16x8*)(Vtg + (size_t)(hh * 64 + d) * TSEQ + t0 + c) = v;
    }
}

// ---------------- layernorm: f32 [T,1024] -> bf16 [T,1024] ----------------
__global__ __launch_bounds__(256)
void ln_kernel(const float* __restrict__ x, const float* __restrict__ sc,
               const float* __restrict__ bi, u16* __restrict__ out)
{
    ln_rows(x, sc, bi, out, blockIdx.x);
}

// ---------------- GEMM: C[M,N] = A[M,K](bf16) * Bt[N,K](bf16)^T [+bias][+gelu][+res] --
// BM=128, BK=64, XOR-swizzled LDS (T2/m173). Split-K via gridDim.z; FUSE_Z1: z==1
// partial additionally adds res + bias (final merge only adds the z0 part).
template<int BN, int GELU_F, int OUT_BF16, int HAS_RES, int HAS_BIAS, int FUSE_Z1 = 0>
__global__ __launch_bounds__(256)
void gemm_kernel(const u16* __restrict__ A, int lda,
                 const u16* __restrict__ Bt, int ldb,
                 const float* __restrict__ bias, const float* __restrict__ res,
                 u16* __restrict__ outb, float* __restrict__ outf0,
                 float* __restrict__ outf1, int M, int N, int Kblk)
{
    constexpr int MI = (BN == 128) ? 4 : 2;
    __shared__ u16 Alds[128 * 64];
    __shared__ u16 Blds[BN * 64];
    const int t = threadIdx.x;
    const int lane = t & 63, w = t >> 6;
    const int g = lane >> 4, fr = lane & 15;
    const int m0 = blockIdx.y * 128, n0 = blockIdx.x * BN;
    const size_t koff = (size_t)blockIdx.z * Kblk;
    const int rowbase = (BN == 128) ? (w >> 1) * 64 : w * 32;
    const int colbase = (BN == 128) ? (w & 1) * 64 : 0;
    float* outf = blockIdx.z ? outf1 : outf0;

    f32x4 zero4 = {0.f, 0.f, 0.f, 0.f};
    f32x4 acc[MI][4];
#pragma unroll
    for (int i = 0; i < MI; i++)
#pragma unroll
        for (int j = 0; j < 4; j++) acc[i][j] = zero4;

    for (int k0 = 0; k0 < Kblk; k0 += 64) {
        __syncthreads();
#pragma unroll
        for (int p = 0; p < 4; p++) {            // A tile: 128x64 = 1024 chunks
            const int c = p * 256 + t;
            const int r = c >> 3, j = (c & 7) ^ (r & 7);
            gload_lds16(A + (size_t)(m0 + r) * lda + koff + k0 + j * 8, Alds + c * 8);
        }
#pragma unroll
        for (int p = 0; p < (BN == 128 ? 4 : 2); p++) {  // B tile: BNx64 chunks
            const int c = p * 256 + t;
            const int r = c >> 3, j = (c & 7) ^ (r & 7);
            gload_lds16(Bt + (size_t)(n0 + r) * ldb + koff + k0 + j * 8, Blds + c * 8);
        }
        __syncthreads();

#pragma unroll
        for (int ks = 0; ks < 2; ks++) {
            bf16x8 af[MI], bfr[4];
#pragma unroll
            for (int i = 0; i < MI; i++)
                af[i] = *(const bf16x8*)(Alds + (rowbase + i * 16 + fr) * 64 + (((ks * 4 + g) ^ (fr & 7)) * 8));
#pragma unroll
            for (int j = 0; j < 4; j++)
                bfr[j] = *(const bf16x8*)(Blds + (colbase + j * 16 + fr) * 64 + (((ks * 4 + g) ^ (fr & 7)) * 8));
#pragma unroll
            for (int i = 0; i < MI; i++)
#pragma unroll
                for (int j = 0; j < 4; j++)
                    acc[i][j] = __builtin_amdgcn_mfma_f32_16x16x32_bf16(af[i], bfr[j], acc[i][j], 0, 0, 0);
        }
    }

    const bool fuse = FUSE_Z1 && (blockIdx.z == 1);
#pragma unroll
    for (int j = 0; j < 4; j++) {
        const int col = n0 + colbase + j * 16 + fr;
        float bv = 0.f;
        if (HAS_BIAS) bv = bias[col];
        if (FUSE_Z1 && fuse) bv = bias[col];
#pragma unroll
        for (int i = 0; i < MI; i++) {
#pragma unroll
            for (int r = 0; r < 4; r++) {
                const int row = m0 + rowbase + i * 16 + g * 4 + r;
                float v = acc[i][j][r] + bv;
                if (GELU_F) {
                    const float q = 0.7978845608028654f * (v + 0.044715f * v * v * v);
                    const float e = exp2_hw(fminf(q, 30.f) * 2.8853900817779268f);
                    v = v * e * rcp_hw(e + 1.0f);
                }
                if (HAS_RES) v += res[(size_t)row * N + col];
                if (FUSE_Z1 && fuse) v += res[(size_t)row * N + col];
                if (OUT_BF16) outb[(size_t)row * N + col] = f2bf(v);
                else          outf[(size_t)row * N + col] = v;
            }
        }
    }
}

// ---------------- GEMM 256x128 (8 waves): C = A*Bt^T + bias, gelu, bf16 out ---------
__global__ __launch_bounds__(512, 2)
void gemm256_kernel(const u16* __restrict__ A, const u16* __restrict__ Bt,
                    const float* __restrict__ bias, u16* __restrict__ outb,
                    int M, int N, int K)
{
    __shared__ u16 Alds[256 * 64];   // 32KB
    __shared__ u16 Blds[128 * 64];   // 16KB
    const int t = threadIdx.x;
    const int lane = t & 63, w = t >> 6;
    const int g = lane >> 4, fr = lane & 15;
    const int m0 = blockIdx.y * 256, n0 = blockIdx.x * 128;
    const int rowbase = (w >> 1) * 64;
    const int colbase = (w & 1) * 64;

    f32x4 zero4 = {0.f, 0.f, 0.f, 0.f};
    f32x4 acc[4][4];
#pragma unroll
    for (int i = 0; i < 4; i++)
#pragma unroll
        for (int j = 0; j < 4; j++) acc[i][j] = zero4;

    for (int k0 = 0; k0 < K; k0 += 64) {
        __syncthreads();
#pragma unroll
        for (int p = 0; p < 4; p++) {            // A tile: 256x64 = 2048 chunks
            const int c = p * 512 + t;
            const int r = c >> 3, j = (c & 7) ^ (r & 7);
            gload_lds16(A + (size_t)(m0 + r) * K + k0 + j * 8, Alds + c * 8);
        }
#pragma unroll
        for (int p = 0; p < 2; p++) {            // B tile: 128x64 = 1024 chunks
            const int c = p * 512 + t;
            const int r = c >> 3, j = (c & 7) ^ (r & 7);
            gload_lds16(Bt + (size_t)(n0 + r) * K + k0 + j * 8, Blds + c * 8);
        }
        __syncthreads();

#pragma unroll
        for (int ks = 0; ks < 2; ks++) {
            bf16x8 af[4], bfr[4];
#pragma unroll
            for (int i = 0; i < 4; i++)
                af[i] = *(const bf16x8*)(Alds + (rowbase + i * 16 + fr) * 64 + (((ks * 4 + g) ^ (fr & 7)) * 8));
#pragma unroll
            for (int j = 0; j < 4; j++)
                bfr[j] = *(const bf16x8*)(Blds + (colbase + j * 16 + fr) * 64 + (((ks * 4 + g) ^ (fr & 7)) * 8));
#pragma unroll
            for (int i = 0; i < 4; i++)
#pragma unroll
                for (int j = 0; j < 4; j++)
                    acc[i][j] = __builtin_amdgcn_mfma_f32_16x16x32_bf16(af[i], bfr[j], acc[i][j], 0, 0, 0);
        }
    }

#pragma unroll
    for (int j = 0; j < 4; j++) {
        const int col = n0 + colbase + j * 16 + fr;
        const float bv = bias[col];
#pragma unroll
        for (int i = 0; i < 4; i++) {
#pragma unroll
            for (int r = 0; r < 4; r++) {
                const int row = m0 + rowbase + i * 16 + g * 4 + r;
                float v = acc[i][j][r] + bv;
                const float q = 0.7978845608028654f * (v + 0.044715f * v * v * v);
                const float e = exp2_hw(fminf(q, 30.f) * 2.8853900817779268f);
                v = v * e * rcp_hw(e + 1.0f);
                outb[(size_t)row * N + col] = f2bf(v);
            }
        }
    }
}

// ---------------- FC2 merge: out += part(z0) ----------------------------------------
__global__ __launch_bounds__(256)
void fc2_merge_kernel(float* __restrict__ out, const float* __restrict__ part)
{
    const int i = blockIdx.x * 256 + threadIdx.x;
    const float4 o = ((const float4*)out)[i];
    const float4 p = ((const float4*)part)[i];
    float4 v;
    v.x = o.x + p.x;
    v.y = o.y + p.y;
    v.z = o.z + p.z;
    v.w = o.w + p.w;
    ((float4*)out)[i] = v;
}

// -------- attn helpers -----------------------------------------------------------
// Diagonal masking hoisted (only ~1 of 33 tiles is diagonal; wave-uniform branch).
__device__ __forceinline__ void mask_diag(f32x4 st[4], int klim, int g)
{
    const float ninf = -__builtin_inff();
#pragma unroll
    for (int ct = 0; ct < 4; ct++)
#pragma unroll
        for (int r = 0; r < 4; r++)
            if (ct * 16 + g * 4 + r > klim) st[ct][r] = ninf;
}

// in-lane online softmax (raw S units) + P pack/write. p = 2^(s*C - m*C).
// Defer-max (T13): keep old m while vm <= m + 64; skip O-rescale when all deferred.
__device__ __forceinline__ void softmax_update(
    const f32x4 st[4], int g, int fr,
    float& mrow, float& lrow, f32x4 o[4], u16* Pl)
{
    const float C = 0.125f * 1.4426950408889634f;
    float m0 = fmaxf(fmaxf(st[0][0], st[0][1]), fmaxf(st[0][2], st[0][3]));
    float m1 = fmaxf(fmaxf(st[1][0], st[1][1]), fmaxf(st[1][2], st[1][3]));
    float m2 = fmaxf(fmaxf(st[2][0], st[2][1]), fmaxf(st[2][2], st[2][3]));
    float m3 = fmaxf(fmaxf(st[3][0], st[3][1]), fmaxf(st[3][2], st[3][3]));
    float vm = fmaxf(fmaxf(m0, m1), fmaxf(m2, m3));
    vm = fmaxf(vm, __shfl_xor(vm, 16));
    vm = fmaxf(vm, __shfl_xor(vm, 32));
    const float mn = (vm <= mrow + 64.f) ? mrow : vm;   // defer-max (T13)
    const float mnC = mn * C;
    float rs = 0.f;
#pragma unroll
    for (int ct = 0; ct < 4; ct++) {
        const float p0 = exp2_hw(__builtin_fmaf(st[ct][0], C, -mnC));
        const float p1 = exp2_hw(__builtin_fmaf(st[ct][1], C, -mnC));
        const float p2 = exp2_hw(__builtin_fmaf(st[ct][2], C, -mnC));
        const float p3 = exp2_hw(__builtin_fmaf(st[ct][3], C, -mnC));
        rs += (p0 + p1) + (p2 + p3);
        uint2 pk;
        pk.x = cvt_pk_bf16(p0, p1);
        pk.y = cvt_pk_bf16(p2, p3);
        const int chunk = ct * 2 + (g >> 1);
        const int addr = fr * 64 + ((chunk ^ (fr & 7)) * 8) + (g & 1) * 4;
        *(uint2*)(Pl + addr) = pk;
    }
    rs += __shfl_xor(rs, 16);
    rs += __shfl_xor(rs, 32);
    const float sc = exp2_hw((mrow - mn) * C);          // ==1 when deferred
    lrow = __builtin_fmaf(lrow, sc, rs);
    const bool nores = (mn == mrow);
    mrow = mn;
    if (!__all(nores)) {
        float scb[4];
#pragma unroll
        for (int j = 0; j < 4; j++) scb[j] = __shfl(sc, g * 4 + j);
#pragma unroll
        for (int dt = 0; dt < 4; dt++)
#pragma unroll
            for (int j = 0; j < 4; j++) o[dt][j] *= scb[j];
    }
}

// ---------------- causal flash attention, paired q-tiles + split-K, 8 waves --------
// Block (i,h): q-tiles A=i, B=63-i (65 tile-units, balanced). Wave-group grp=w>>2
// takes k-tiles of parity grp; groups merge m/l/O via LDS at the end. KVBLK=128/iter
// double-buffer staged via global_load_lds, XOR-swizzled (T2/m173). LDS 80KB -> 2
// blocks/CU max BY LDS — so __launch_bounds__(512,2) (VGPR cap 128) is the correct
// bound: (512,4)'s 64-VGPR cap was pure over-constraint (LDS can't fit 4 blocks
// anyway) and made R14's mask-hoist+setprio spill. With cap 128 they fit.
__global__ __launch_bounds__(512, 2)
void attn_kernel(const u16* __restrict__ qkv, const u16* __restrict__ Vtg,
                 u16* __restrict__ y)
{
    __shared__ u16 Klds[2][128 * 64];   // [k=128][d=64]
    __shared__ u16 Vlds[2][64 * 128];   // [d=64][k=128]
    __shared__ u16 Plds[8][16 * 64];
    const int t = threadIdx.x, lane = t & 63, w = t >> 6;
    const int g = lane >> 4, fr = lane & 15;
    const int wv = w & 3, grp = w >> 2;
    const int hh = blockIdx.y;
    const int ii = blockIdx.x;                 // pair (ii, 63-ii)
    const int ntB = 64 - ii;
    const int qAw = ii * 64 + wv * 16;
    const int qBw = (63 - ii) * 64 + wv * 16;

    // Q fragments: lane (g,fr) holds Q[qw+fr][d = ds*32 + g*8 + i]
    bf16x8 aqA[2], aqB[2];
#pragma unroll
    for (int s = 0; s < 2; s++) {
        aqA[s] = *(const bf16x8*)(qkv + (size_t)(qAw + fr) * 3072 + hh * 64 + s * 32 + g * 8);
        aqB[s] = *(const bf16x8*)(qkv + (size_t)(qBw + fr) * 3072 + hh * 64 + s * 32 + g * 8);
    }

    f32x4 zero4 = {0.f, 0.f, 0.f, 0.f};
    f32x4 oA[4] = {zero4, zero4, zero4, zero4};
    f32x4 oB[4] = {zero4, zero4, zero4, zero4};
    const float ninf = -__builtin_inff();
    float mA = ninf, lA = 0.f, mB = ninf, lB = 0.f;

    // staging: K tile [k=128][d=64] as 1024 chunks [r=c>>3][j], V tile [d=64][k=128]
    // as 1024 chunks [d=c>>4][cj]; dest linear, src XOR-swizzled (grp-half bit kept).
    const int cK0 = t, cK1 = t + 512;
    const int rK0 = cK0 >> 3, jK0 = (cK0 & 7) ^ (rK0 & 7);
    const int rK1 = cK1 >> 3, jK1 = (cK1 & 7) ^ (rK1 & 7);
    const int rv0 = cK0 >> 4, cj0 = cK0 & 15;
    const int jv0 = (cj0 & 8) | ((cj0 & 7) ^ (rv0 & 7));
    const int rv1 = cK1 >> 4, cj1 = cK1 & 15;
    const int jv1 = (cj1 & 8) | ((cj1 & 7) ^ (rv1 & 7));
    const u16* gk0 = qkv + (size_t)rK0 * 3072 + 1024 + hh * 64 + jK0 * 8;
    const u16* gk1 = qkv + (size_t)rK1 * 3072 + 1024 + hh * 64 + jK1 * 8;
    const u16* gv0 = Vtg + (size_t)(hh * 64 + rv0) * TSEQ + jv0 * 8;
    const u16* gv1 = Vtg + (size_t)(hh * 64 + rv1) * TSEQ + jv1 * 8;

#define STAGE(buf, k0) do { \
        gload_lds16(gk0 + (size_t)(k0) * 3072, Klds[buf] + cK0 * 8); \
        gload_lds16(gk1 + (size_t)(k0) * 3072, Klds[buf] + cK1 * 8); \
        gload_lds16(gv0 + (k0), Vlds[buf] + cK0 * 8); \
        gload_lds16(gv1 + (k0), Vlds[buf] + cK1 * 8); \
    } while (0)

    const int nIter = (65 - ii) >> 1;
    STAGE(0, 0);

    int cur = 0;
    for (int j = 0; j < nIter; j++) {
        __syncthreads();   // drains stage(j); all waves done reading buf[cur^1]
        if (j + 1 < nIter) STAGE(cur ^ 1, (j + 1) * 128);

        const int kt = 2 * j + grp;
        const bool aB = kt < ntB;
        const bool aA = kt <= ii;
        if (aB | aA) {
            const u16* Kl = Klds[cur] + grp * (64 * 64);
            const u16* Vl = Vlds[cur];
            const int klim = wv * 16 + fr;

            // S^T frags: st[ct][r] = S[k_local=ct*16+g*4+r][q=qw+fr]
            f32x4 stA[4] = {zero4, zero4, zero4, zero4};
            f32x4 stB[4] = {zero4, zero4, zero4, zero4};
            __builtin_amdgcn_s_setprio(1);
#pragma unroll
            for (int ct = 0; ct < 4; ct++) {
#pragma unroll
                for (int ds = 0; ds < 2; ds++) {
                    const bf16x8 bk = *(const bf16x8*)(Kl + (ct * 16 + fr) * 64 + (((ds * 4 + g) ^ (fr & 7)) * 8));
                    if (aB) stB[ct] = __builtin_amdgcn_mfma_f32_16x16x32_bf16(bk, aqB[ds], stB[ct], 0, 0, 0);
                    if (aA) stA[ct] = __builtin_amdgcn_mfma_f32_16x16x32_bf16(bk, aqA[ds], stA[ct], 0, 0, 0);
                }
            }
            __builtin_amdgcn_s_setprio(0);

            if (aB) {
                if (kt == ntB - 1) mask_diag(stB, klim, g);
                softmax_update(stB, g, fr, mB, lB, oB, Plds[w]);
                __builtin_amdgcn_s_waitcnt(0xc07f);   // lgkmcnt(0): own P writes visible
                __builtin_amdgcn_s_setprio(1);
#pragma unroll
                for (int kkh = 0; kkh < 2; kkh++) {
                    const bf16x8 pa = *(const bf16x8*)(&Plds[w][fr * 64 + (((kkh * 4 + g) ^ (fr & 7)) * 8)]);
#pragma unroll
                    for (int dt = 0; dt < 4; dt++) {
                        const int cc = grp * 8 + kkh * 4 + g;
                        const bf16x8 bv = *(const bf16x8*)(Vl + (dt * 16 + fr) * 128 + (((cc & 8) | ((cc & 7) ^ (fr & 7))) * 8));
                        oB[dt] = __builtin_amdgcn_mfma_f32_16x16x32_bf16(pa, bv, oB[dt], 0, 0, 0);
                    }
                }
                __builtin_amdgcn_s_setprio(0);
            }
            if (aA) {
                if (kt == ii) mask_diag(stA, klim, g);
                softmax_update(stA, g, fr, mA, lA, oA, Plds[w]);
                __builtin_amdgcn_s_waitcnt(0xc07f);
                __builtin_amdgcn_s_setprio(1);
#pragma unroll
                for (int kkh = 0; kkh < 2; kkh++) {
                    const bf16x8 pa = *(const bf16x8*)(&Plds[w][fr * 64 + (((kkh * 4 + g) ^ (fr & 7)) * 8)]);
#pragma unroll
                    for (int dt = 0; dt < 4; dt++) {
                        const int cc = grp * 8 + kkh * 4 + g;
                        const bf16x8 bv = *(const bf16x8*)(Vl + (dt * 16 + fr) * 128 + (((cc & 8) | ((cc & 7) ^ (fr & 7))) * 8));
                        oA[dt] = __builtin_amdgcn_mfma_f32_16x16x32_bf16(pa, bv, oA[dt], 0, 0, 0);
                    }
                }
                __builtin_amdgcn_s_setprio(0);
            }
        }
        cur ^= 1;
    }
#undef STAGE

    // ---- split-K merge: group1 -> LDS, group0 merges + writes ----
    __syncthreads();                      // all staging/compute done; reuse K/V LDS
    float* Of = (float*)&Klds[0][0];      // [wv][s][16q][64d] f32 = 32KB
    float2* Ml = (float2*)&Vlds[0][0];    // [wv][s][16q] {m,l}
    const float C = 0.125f * 1.4426950408889634f;
    if (grp == 1) {
#pragma unroll
        for (int dt = 0; dt < 4; dt++)
#pragma unroll
            for (int jq = 0; jq < 4; jq++) {
                Of[((wv * 2 + 0) * 16 + g * 4 + jq) * 64 + dt * 16 + fr] = oA[dt][jq];
                Of[((wv * 2 + 1) * 16 + g * 4 + jq) * 64 + dt * 16 + fr] = oB[dt][jq];
            }
        if (g == 0) {
            Ml[(wv * 2 + 0) * 16 + fr] = make_float2(mA, lA);
            Ml[(wv * 2 + 1) * 16 + fr] = make_float2(mB, lB);
        }
    }
    __syncthreads();
    if (grp == 0) {
#pragma unroll
        for (int jq = 0; jq < 4; jq++) {
            // tile A
            {
                const float m0 = __shfl(mA, g * 4 + jq), l0 = __shfl(lA, g * 4 + jq);
                const float2 ml1 = Ml[(wv * 2 + 0) * 16 + g * 4 + jq];
                const float mm = fmaxf(m0, ml1.x);
                const float s0 = exp2_hw((m0 - mm) * C);
                const float s1 = exp2_hw((ml1.x - mm) * C);
                const float rl = rcp_hw(__builtin_fmaf(l0, s0, ml1.y * s1));
#pragma unroll
                for (int dt = 0; dt < 4; dt++) {
                    const float o1 = Of[((wv * 2 + 0) * 16 + g * 4 + jq) * 64 + dt * 16 + fr];
                    y[(size_t)(qAw + g * 4 + jq) * DMODEL + hh * 64 + dt * 16 + fr] =
                        f2bf((oA[dt][jq] * s0 + o1 * s1) * rl);
                }
            }
            // tile B
            {
                const float m0 = __shfl(mB, g * 4 + jq), l0 = __shfl(lB, g * 4 + jq);
                const float2 ml1 = Ml[(wv * 2 + 1) * 16 + g * 4 + jq];
                const float mm = fmaxf(m0, ml1.x);
                const float s0 = exp2_hw((m0 - mm) * C);
                const float s1 = exp2_hw((ml1.x - mm) * C);
                const float rl = rcp_hw(__builtin_fmaf(l0, s0, ml1.y * s1));
#pragma unroll
                for (int dt = 0; dt < 4; dt++) {
                    const float o1 = Of[((wv * 2 + 1) * 16 + g * 4 + jq) * 64 + dt * 16 + fr];
                    y[(size_t)(qBw + g * 4 + jq) * DMODEL + hh * 64 + dt * 16 + fr] =
                        f2bf((oB[dt][jq] * s0 + o1 * s1) * rl);
                }
            }
        }
    }
}

extern "C" void kernel_launch(void* const* d_in, const int* in_sizes, int n_in,
                              void* d_out, int out_size, void* d_ws, size_t ws_size,
                              hipStream_t stream)
{
    const float* x      = (const float*)d_in[0];
    const float* ln1_s  = (const float*)d_in[1];
    const float* ln1_b  = (const float*)d_in[2];
    const float* W_attn = (const float*)d_in[3];
    const float* b_attn = (const float*)d_in[4];
    const float* W_proj = (const float*)d_in[5];
    const float* b_proj = (const float*)d_in[6];
    const float* ln2_s  = (const float*)d_in[7];
    const float* ln2_b  = (const float*)d_in[8];
    const float* W_fc   = (const float*)d_in[9];
    const float* b_fc   = (const float*)d_in[10];
    const float* W_fc2  = (const float*)d_in[11];
    const float* b_fc2  = (const float*)d_in[12];
    float* out = (float*)d_out;

    char* ws = (char*)d_ws;
    u16* WtAttn = (u16*)ws; ws += (size_t)3072 * 1024 * 2;
    u16* WtProj = (u16*)ws; ws += (size_t)1024 * 1024 * 2;
    u16* WtFc   = (u16*)ws; ws += (size_t)4096 * 1024 * 2;
    u16* WtFc2  = (u16*)ws; ws += (size_t)1024 * 4096 * 2;
    u16* bufA   = (u16*)ws; ws += (size_t)4096 * 1024 * 2;  // h / y / h2
    u16* bufB   = (u16*)ws; ws += (size_t)4096 * 4096 * 2;  // qkv / m
    float* x1   = (float*)ws; ws += (size_t)4096 * 1024 * 4;
    u16* Vtg    = (u16*)x1;      // alias: x1 not live until proj GEMM; Vt dead by then
    float* P0   = (float*)d_ws;  // FC2 partial: overlays WtAttn+WtProj+WtFc (dead then)

    // fused prep: 4 weight transposes + ln1 (all independent), one launch
    prep_kernel<<<4096, 256, 0, stream>>>(x, ln1_s, ln1_b, bufA,
                                          W_attn, WtAttn, W_proj, WtProj,
                                          W_fc, WtFc, W_fc2, WtFc2);

    // attention branch
    gemm_kernel<128, 0, 1, 0, 1><<<dim3(24, 32, 1), 256, 0, stream>>>(
        bufA, 1024, WtAttn, 1024, b_attn, nullptr, bufB, nullptr, nullptr, 4096, 3072, 1024);
    v_transpose_kernel<<<dim3(TSEQ / 64, NHEAD), 256, 0, stream>>>(bufB, Vtg);
    attn_kernel<<<dim3(32, NHEAD), 512, 0, stream>>>(bufB, Vtg, bufA);
    gemm_kernel<64, 0, 0, 1, 1><<<dim3(16, 32, 1), 256, 0, stream>>>(
        bufA, 1024, WtProj, 1024, b_proj, x, nullptr, x1, nullptr, 4096, 1024, 1024);

    // MLP branch
    ln_kernel<<<TSEQ / 4, 256, 0, stream>>>(x1, ln2_s, ln2_b, bufA);
    gemm256_kernel<<<dim3(32, 16), 512, 0, stream>>>(
        bufA, WtFc, b_fc, bufB, 4096, 4096, 1024);
    // FC2 split-K=2: z=0 -> P0 partial; z=1 -> out with x1 + b_fc2 fused (FUSE_Z1)
    gemm_kernel<128, 0, 0, 0, 0, 1><<<dim3(8, 32, 2), 256, 0, stream>>>(
        bufB, 4096, WtFc2, 4096, b_fc2, x1, nullptr, P0, out, 4096, 1024, 2048);
    fc2_merge_kernel<<<4096, 256, 0, stream>>>(out, P0);
}

// Round 17
// 275.791 us; speedup vs baseline: 1.3176x; 1.3176x over previous
//
#include <hip/hip_runtime.h>
#include <hip/hip_bf16.h>

typedef short bf16x8 __attribute__((ext_vector_type(8)));
typedef float f32x4 __attribute__((ext_vector_type(4)));
typedef unsigned short u16;
typedef unsigned int u32;

// dims (fixed per problem)
#define TSEQ 4096
#define DMODEL 1024
#define NHEAD 16
#define DHEAD 64
#define DFF 4096

__device__ __forceinline__ u16 f2bf(float f) {
    u32 u = __builtin_bit_cast(u32, f);
    u32 lsb = (u >> 16) & 1u;
    u += 0x7fffu + lsb;
    return (u16)(u >> 16);
}

__device__ __forceinline__ float exp2_hw(float x) {   // 2^x
    float r;
    asm("v_exp_f32 %0, %1" : "=v"(r) : "v"(x));
    return r;
}

__device__ __forceinline__ float rcp_hw(float x) {    // 1/x (approx, ~1ulp)
    float r;
    asm("v_rcp_f32 %0, %1" : "=v"(r) : "v"(x));
    return r;
}

__device__ __forceinline__ u32 cvt_pk_bf16(float a, float b) {  // lo=bf16(a), hi=bf16(b)
    u32 r;
    asm("v_cvt_pk_bf16_f32 %0, %1, %2" : "=v"(r) : "v"(a), "v"(b));
    return r;
}

__device__ __forceinline__ void gload_lds16(const u16* g, u16* l) {
    __builtin_amdgcn_global_load_lds(
        (const __attribute__((address_space(1))) u32*)g,
        (__attribute__((address_space(3))) u32*)l, 16, 0, 0);
}

// T1 XCD swizzle (m157/m204): same-row-panel blocks -> same XCD's L2.
// Requires gridDim.x*gridDim.y % 8 == 0 (all our GEMM grids qualify).
__device__ __forceinline__ void xcd_swizzle(int& bx, int& by) {
    const int gx = gridDim.x;
    const int nwg = gx * gridDim.y;
    const int flat = by * gx + bx;
    const int q = nwg >> 3;
    const int swz = (flat & 7) * q + (flat >> 3);
    bx = swz % gx;
    by = swz / gx;
}

// ---------------- fused prep: 4x weight transpose+cast AND ln1, one launch ----------
__device__ __forceinline__ void transpose_tile(
    const float* __restrict__ W, u16* __restrict__ Wt, int K, int N, int bx, int by,
    float (*tile)[65])
{
    const int t = threadIdx.x;
    const int c = t & 63, r4 = t >> 6;
    const int col0 = bx * 64;  // N dim
    const int row0 = by * 64;  // K dim
#pragma unroll
    for (int p = 0; p < 16; p++) {
        const int r = 4 * p + r4;
        tile[r][c] = W[(size_t)(row0 + r) * N + col0 + c];
    }
    __syncthreads();
#pragma unroll
    for (int p = 0; p < 16; p++) {
        const int r = 4 * p + r4;
        Wt[(size_t)(col0 + r) * K + row0 + c] = f2bf(tile[c][r]);
    }
}

__device__ __forceinline__ void ln_rows(
    const float* __restrict__ x, const float* __restrict__ sc,
    const float* __restrict__ bi, u16* __restrict__ out, int blk)
{
    const int lane = threadIdx.x & 63;
    const int row = blk * 4 + (threadIdx.x >> 6);
    const float* xr = x + (size_t)row * DMODEL;
    float4 v[4];
    float s = 0.f, s2 = 0.f;
#pragma unroll
    for (int q = 0; q < 4; q++) {
        v[q] = *(const float4*)(xr + 4 * (lane + 64 * q));
        s  += v[q].x + v[q].y + v[q].z + v[q].w;
        s2 += v[q].x * v[q].x + v[q].y * v[q].y + v[q].z * v[q].z + v[q].w * v[q].w;
    }
#pragma unroll
    for (int off = 1; off < 64; off <<= 1) {
        s  += __shfl_xor(s, off);
        s2 += __shfl_xor(s2, off);
    }
    const float mu = s * (1.f / DMODEL);
    const float rstd = rsqrtf(s2 * (1.f / DMODEL) - mu * mu + 1e-5f);
#pragma unroll
    for (int q = 0; q < 4; q++) {
        const int c = 4 * (lane + 64 * q);
        const float4 scv = *(const float4*)(sc + c);
        const float4 biv = *(const float4*)(bi + c);
        ushort4 ov;
        ov.x = f2bf((v[q].x - mu) * rstd * scv.x + biv.x);
        ov.y = f2bf((v[q].y - mu) * rstd * scv.y + biv.y);
        ov.z = f2bf((v[q].z - mu) * rstd * scv.z + biv.z);
        ov.w = f2bf((v[q].w - mu) * rstd * scv.w + biv.w);
        *(ushort4*)(out + (size_t)row * DMODEL + c) = ov;
    }
}

__global__ __launch_bounds__(256)
void prep_kernel(const float* __restrict__ x, const float* __restrict__ ln1_s,
                 const float* __restrict__ ln1_b, u16* __restrict__ h,
                 const float* __restrict__ W_attn, u16* __restrict__ WtAttn,
                 const float* __restrict__ W_proj, u16* __restrict__ WtProj,
                 const float* __restrict__ W_fc,   u16* __restrict__ WtFc,
                 const float* __restrict__ W_fc2,  u16* __restrict__ WtFc2)
{
    __shared__ float tile[64][65];
    int b = blockIdx.x;
    if (b < 1024) { ln_rows(x, ln1_s, ln1_b, h, b); return; }
    b -= 1024;
    if (b < 768)  { transpose_tile(W_attn, WtAttn, 1024, 3072, b % 48, b / 48, tile); return; }
    b -= 768;
    if (b < 256)  { transpose_tile(W_proj, WtProj, 1024, 1024, b % 16, b / 16, tile); return; }
    b -= 256;
    if (b < 1024) { transpose_tile(W_fc,   WtFc,   1024, 4096, b % 64, b / 64, tile); return; }
    b -= 1024;
    transpose_tile(W_fc2, WtFc2, 4096, 1024, b % 16, b / 16, tile);
}

// ---------------- V transpose: qkv bf16 [T,3072] V-part -> Vt[h][d][T] bf16 ----------
__global__ __launch_bounds__(256)
void v_transpose_kernel(const u16* __restrict__ qkv, u16* __restrict__ Vtg)
{
    __shared__ u16 tile[64][72];
    const int t = threadIdx.x;
    const int hh = blockIdx.y, t0 = blockIdx.x * 64;
#pragma unroll
    for (int p = 0; p < 2; p++) {
        const int L = p * 2048 + t * 8;
        const int r = L >> 6, c = L & 63;
        const bf16x8 v = *(const bf16x8*)(qkv + (size_t)(t0 + r) * 3072 + 2048 + hh * 64 + c);
#pragma unroll
        for (int i = 0; i < 8; i++) tile[c + i][r] = (u16)v[i];
    }
    __syncthreads();
#pragma unroll
    for (int p = 0; p < 2; p++) {
        const int L = p * 2048 + t * 8;
        const int d = L >> 6, c = L & 63;
        bf16x8 v;
#pragma unroll
        for (int i = 0; i < 8; i++) v[i] = (short)tile[d][c + i];
        *(bf16x8*)(Vtg + (size_t)(hh * 64 + d) * TSEQ + t0 + c) = v;
    }
}

// ---------------- layernorm: f32 [T,1024] -> bf16 [T,1024] ----------------
__global__ __launch_bounds__(256)
void ln_kernel(const float* __restrict__ x, const float* __restrict__ sc,
               const float* __restrict__ bi, u16* __restrict__ out)
{
    ln_rows(x, sc, bi, out, blockIdx.x);
}

// ---------------- GEMM: C[M,N] = A[M,K](bf16) * Bt[N,K](bf16)^T [+bias][+gelu][+res] --
// BM=128, BK=64, XOR-swizzled LDS (T2/m173). Split-K via gridDim.z; FUSE_Z1: z==1
// partial additionally adds res + bias (final merge only adds the z0 part).
template<int BN, int GELU_F, int OUT_BF16, int HAS_RES, int HAS_BIAS, int FUSE_Z1 = 0>
__global__ __launch_bounds__(256)
void gemm_kernel(const u16* __restrict__ A, int lda,
                 const u16* __restrict__ Bt, int ldb,
                 const float* __restrict__ bias, const float* __restrict__ res,
                 u16* __restrict__ outb, float* __restrict__ outf0,
                 float* __restrict__ outf1, int M, int N, int Kblk)
{
    constexpr int MI = (BN == 128) ? 4 : 2;
    __shared__ u16 Alds[128 * 64];
    __shared__ u16 Blds[BN * 64];
    const int t = threadIdx.x;
    const int lane = t & 63, w = t >> 6;
    const int g = lane >> 4, fr = lane & 15;
    int bx = blockIdx.x, by = blockIdx.y;
    xcd_swizzle(bx, by);                       // T1: L2 locality
    const int m0 = by * 128, n0 = bx * BN;
    const size_t koff = (size_t)blockIdx.z * Kblk;
    const int rowbase = (BN == 128) ? (w >> 1) * 64 : w * 32;
    const int colbase = (BN == 128) ? (w & 1) * 64 : 0;
    float* outf = blockIdx.z ? outf1 : outf0;

    f32x4 zero4 = {0.f, 0.f, 0.f, 0.f};
    f32x4 acc[MI][4];
#pragma unroll
    for (int i = 0; i < MI; i++)
#pragma unroll
        for (int j = 0; j < 4; j++) acc[i][j] = zero4;

    for (int k0 = 0; k0 < Kblk; k0 += 64) {
        __syncthreads();
#pragma unroll
        for (int p = 0; p < 4; p++) {            // A tile: 128x64 = 1024 chunks
            const int c = p * 256 + t;
            const int r = c >> 3, j = (c & 7) ^ (r & 7);
            gload_lds16(A + (size_t)(m0 + r) * lda + koff + k0 + j * 8, Alds + c * 8);
        }
#pragma unroll
        for (int p = 0; p < (BN == 128 ? 4 : 2); p++) {  // B tile: BNx64 chunks
            const int c = p * 256 + t;
            const int r = c >> 3, j = (c & 7) ^ (r & 7);
            gload_lds16(Bt + (size_t)(n0 + r) * ldb + koff + k0 + j * 8, Blds + c * 8);
        }
        __syncthreads();

#pragma unroll
        for (int ks = 0; ks < 2; ks++) {
            bf16x8 af[MI], bfr[4];
#pragma unroll
            for (int i = 0; i < MI; i++)
                af[i] = *(const bf16x8*)(Alds + (rowbase + i * 16 + fr) * 64 + (((ks * 4 + g) ^ (fr & 7)) * 8));
#pragma unroll
            for (int j = 0; j < 4; j++)
                bfr[j] = *(const bf16x8*)(Blds + (colbase + j * 16 + fr) * 64 + (((ks * 4 + g) ^ (fr & 7)) * 8));
#pragma unroll
            for (int i = 0; i < MI; i++)
#pragma unroll
                for (int j = 0; j < 4; j++)
                    acc[i][j] = __builtin_amdgcn_mfma_f32_16x16x32_bf16(af[i], bfr[j], acc[i][j], 0, 0, 0);
        }
    }

    const bool fuse = FUSE_Z1 && (blockIdx.z == 1);
#pragma unroll
    for (int j = 0; j < 4; j++) {
        const int col = n0 + colbase + j * 16 + fr;
        float bv = 0.f;
        if (HAS_BIAS) bv = bias[col];
        if (FUSE_Z1 && fuse) bv = bias[col];
#pragma unroll
        for (int i = 0; i < MI; i++) {
#pragma unroll
            for (int r = 0; r < 4; r++) {
                const int row = m0 + rowbase + i * 16 + g * 4 + r;
                float v = acc[i][j][r] + bv;
                if (GELU_F) {
                    const float q = 0.7978845608028654f * (v + 0.044715f * v * v * v);
                    const float e = exp2_hw(fminf(q, 30.f) * 2.8853900817779268f);
                    v = v * e * rcp_hw(e + 1.0f);
                }
                if (HAS_RES) v += res[(size_t)row * N + col];
                if (FUSE_Z1 && fuse) v += res[(size_t)row * N + col];
                if (OUT_BF16) outb[(size_t)row * N + col] = f2bf(v);
                else          outf[(size_t)row * N + col] = v;
            }
        }
    }
}

// ---------------- GEMM 256x128 (8 waves): C = A*Bt^T + bias, gelu, bf16 out ---------
__global__ __launch_bounds__(512, 2)
void gemm256_kernel(const u16* __restrict__ A, const u16* __restrict__ Bt,
                    const float* __restrict__ bias, u16* __restrict__ outb,
                    int M, int N, int K)
{
    __shared__ u16 Alds[256 * 64];   // 32KB
    __shared__ u16 Blds[128 * 64];   // 16KB
    const int t = threadIdx.x;
    const int lane = t & 63, w = t >> 6;
    const int g = lane >> 4, fr = lane & 15;
    int bx = blockIdx.x, by = blockIdx.y;
    xcd_swizzle(bx, by);                       // T1: L2 locality
    const int m0 = by * 256, n0 = bx * 128;
    const int rowbase = (w >> 1) * 64;
    const int colbase = (w & 1) * 64;

    f32x4 zero4 = {0.f, 0.f, 0.f, 0.f};
    f32x4 acc[4][4];
#pragma unroll
    for (int i = 0; i < 4; i++)
#pragma unroll
        for (int j = 0; j < 4; j++) acc[i][j] = zero4;

    for (int k0 = 0; k0 < K; k0 += 64) {
        __syncthreads();
#pragma unroll
        for (int p = 0; p < 4; p++) {            // A tile: 256x64 = 2048 chunks
            const int c = p * 512 + t;
            const int r = c >> 3, j = (c & 7) ^ (r & 7);
            gload_lds16(A + (size_t)(m0 + r) * K + k0 + j * 8, Alds + c * 8);
        }
#pragma unroll
        for (int p = 0; p < 2; p++) {            // B tile: 128x64 = 1024 chunks
            const int c = p * 512 + t;
            const int r = c >> 3, j = (c & 7) ^ (r & 7);
            gload_lds16(Bt + (size_t)(n0 + r) * K + k0 + j * 8, Blds + c * 8);
        }
        __syncthreads();

#pragma unroll
        for (int ks = 0; ks < 2; ks++) {
            bf16x8 af[4], bfr[4];
#pragma unroll
            for (int i = 0; i < 4; i++)
                af[i] = *(const bf16x8*)(Alds + (rowbase + i * 16 + fr) * 64 + (((ks * 4 + g) ^ (fr & 7)) * 8));
#pragma unroll
            for (int j = 0; j < 4; j++)
                bfr[j] = *(const bf16x8*)(Blds + (colbase + j * 16 + fr) * 64 + (((ks * 4 + g) ^ (fr & 7)) * 8));
#pragma unroll
            for (int i = 0; i < 4; i++)
#pragma unroll
                for (int j = 0; j < 4; j++)
                    acc[i][j] = __builtin_amdgcn_mfma_f32_16x16x32_bf16(af[i], bfr[j], acc[i][j], 0, 0, 0);
        }
    }

#pragma unroll
    for (int j = 0; j < 4; j++) {
        const int col = n0 + colbase + j * 16 + fr;
        const float bv = bias[col];
#pragma unroll
        for (int i = 0; i < 4; i++) {
#pragma unroll
            for (int r = 0; r < 4; r++) {
                const int row = m0 + rowbase + i * 16 + g * 4 + r;
                float v = acc[i][j][r] + bv;
                const float q = 0.7978845608028654f * (v + 0.044715f * v * v * v);
                const float e = exp2_hw(fminf(q, 30.f) * 2.8853900817779268f);
                v = v * e * rcp_hw(e + 1.0f);
                outb[(size_t)row * N + col] = f2bf(v);
            }
        }
    }
}

// ---------------- FC2 merge: out += part(z0) ----------------------------------------
__global__ __launch_bounds__(256)
void fc2_merge_kernel(float* __restrict__ out, const float* __restrict__ part)
{
    const int i = blockIdx.x * 256 + threadIdx.x;
    const float4 o = ((const float4*)out)[i];
    const float4 p = ((const float4*)part)[i];
    float4 v;
    v.x = o.x + p.x;
    v.y = o.y + p.y;
    v.z = o.z + p.z;
    v.w = o.w + p.w;
    ((float4*)out)[i] = v;
}

// -------- attn helper: in-lane online softmax (raw S units) + P pack/write ----------
// p = exp(0.125*(s - m)) = 2^(s*C - m*C), C = 0.125*log2(e). Defer-max: keep old m
// while vm <= m + 64 (== 8 scaled); skip O-rescale when all rows deferred.
// FROZEN (R14/R16 lessons): masking stays inline, no setprio, bounds (512,4).
// Any change that grows VGPR past 64 either spills (R14, at cap 64) or halves
// resident waves (R16, VGPR 112 at cap 128): both ~2-7x slowdowns.
__device__ __forceinline__ void softmax_update(
    const f32x4 st[4], bool diag, int klim, int g, int fr,
    float& mrow, float& lrow, f32x4 o[4], u16* Pl)
{
    const float ninf = -__builtin_inff();
    const float C = 0.125f * 1.4426950408889634f;
    float av[4][4];
#pragma unroll
    for (int ct = 0; ct < 4; ct++)
#pragma unroll
        for (int r = 0; r < 4; r++) {
            float aa = st[ct][r];
            if (diag && (ct * 16 + g * 4 + r) > klim) aa = ninf;
            av[ct][r] = aa;
        }
    float m0 = fmaxf(fmaxf(av[0][0], av[0][1]), fmaxf(av[0][2], av[0][3]));
    float m1 = fmaxf(fmaxf(av[1][0], av[1][1]), fmaxf(av[1][2], av[1][3]));
    float m2 = fmaxf(fmaxf(av[2][0], av[2][1]), fmaxf(av[2][2], av[2][3]));
    float m3 = fmaxf(fmaxf(av[3][0], av[3][1]), fmaxf(av[3][2], av[3][3]));
    float vm = fmaxf(fmaxf(m0, m1), fmaxf(m2, m3));
    vm = fmaxf(vm, __shfl_xor(vm, 16));
    vm = fmaxf(vm, __shfl_xor(vm, 32));
    const float mn = (vm <= mrow + 64.f) ? mrow : vm;   // defer-max (T13)
    const float mnC = mn * C;
    float rs = 0.f;
#pragma unroll
    for (int ct = 0; ct < 4; ct++) {
        const float p0 = exp2_hw(__builtin_fmaf(av[ct][0], C, -mnC));
        const float p1 = exp2_hw(__builtin_fmaf(av[ct][1], C, -mnC));
        const float p2 = exp2_hw(__builtin_fmaf(av[ct][2], C, -mnC));
        const float p3 = exp2_hw(__builtin_fmaf(av[ct][3], C, -mnC));
        rs += (p0 + p1) + (p2 + p3);
        uint2 pk;
        pk.x = cvt_pk_bf16(p0, p1);
        pk.y = cvt_pk_bf16(p2, p3);
        const int chunk = ct * 2 + (g >> 1);
        const int addr = fr * 64 + ((chunk ^ (fr & 7)) * 8) + (g & 1) * 4;
        *(uint2*)(Pl + addr) = pk;
    }
    rs += __shfl_xor(rs, 16);
    rs += __shfl_xor(rs, 32);
    const float sc = exp2_hw((mrow - mn) * C);          // ==1 when deferred
    lrow = __builtin_fmaf(lrow, sc, rs);
    const bool nores = (mn == mrow);
    mrow = mn;
    if (!__all(nores)) {
        float scb[4];
#pragma unroll
        for (int j = 0; j < 4; j++) scb[j] = __shfl(sc, g * 4 + j);
#pragma unroll
        for (int dt = 0; dt < 4; dt++)
#pragma unroll
            for (int j = 0; j < 4; j++) o[dt][j] *= scb[j];
    }
}

// ---------------- causal flash attention, paired q-tiles + split-K, 8 waves --------
// EXACTLY the R12 body (89.4us, VGPR 64, no spill). FROZEN — see softmax_update note.
__global__ __launch_bounds__(512, 4)
void attn_kernel(const u16* __restrict__ qkv, const u16* __restrict__ Vtg,
                 u16* __restrict__ y)
{
    __shared__ u16 Klds[2][128 * 64];   // [k=128][d=64]
    __shared__ u16 Vlds[2][64 * 128];   // [d=64][k=128]
    __shared__ u16 Plds[8][16 * 64];
    const int t = threadIdx.x, lane = t & 63, w = t >> 6;
    const int g = lane >> 4, fr = lane & 15;
    const int wv = w & 3, grp = w >> 2;
    const int hh = blockIdx.y;
    const int ii = blockIdx.x;                 // pair (ii, 63-ii)
    const int ntB = 64 - ii;
    const int qAw = ii * 64 + wv * 16;
    const int qBw = (63 - ii) * 64 + wv * 16;

    // Q fragments: lane (g,fr) holds Q[qw+fr][d = ds*32 + g*8 + i]
    bf16x8 aqA[2], aqB[2];
#pragma unroll
    for (int s = 0; s < 2; s++) {
        aqA[s] = *(const bf16x8*)(qkv + (size_t)(qAw + fr) * 3072 + hh * 64 + s * 32 + g * 8);
        aqB[s] = *(const bf16x8*)(qkv + (size_t)(qBw + fr) * 3072 + hh * 64 + s * 32 + g * 8);
    }

    f32x4 zero4 = {0.f, 0.f, 0.f, 0.f};
    f32x4 oA[4] = {zero4, zero4, zero4, zero4};
    f32x4 oB[4] = {zero4, zero4, zero4, zero4};
    const float ninf = -__builtin_inff();
    float mA = ninf, lA = 0.f, mB = ninf, lB = 0.f;

    // staging: K tile [k=128][d=64] as 1024 chunks [r=c>>3][j], V tile [d=64][k=128]
    // as 1024 chunks [d=c>>4][cj]; dest linear, src XOR-swizzled (grp-half bit kept).
    const int cK0 = t, cK1 = t + 512;
    const int rK0 = cK0 >> 3, jK0 = (cK0 & 7) ^ (rK0 & 7);
    const int rK1 = cK1 >> 3, jK1 = (cK1 & 7) ^ (rK1 & 7);
    const int rv0 = cK0 >> 4, cj0 = cK0 & 15;
    const int jv0 = (cj0 & 8) | ((cj0 & 7) ^ (rv0 & 7));
    const int rv1 = cK1 >> 4, cj1 = cK1 & 15;
    const int jv1 = (cj1 & 8) | ((cj1 & 7) ^ (rv1 & 7));
    const u16* gk0 = qkv + (size_t)rK0 * 3072 + 1024 + hh * 64 + jK0 * 8;
    const u16* gk1 = qkv + (size_t)rK1 * 3072 + 1024 + hh * 64 + jK1 * 8;
    const u16* gv0 = Vtg + (size_t)(hh * 64 + rv0) * TSEQ + jv0 * 8;
    const u16* gv1 = Vtg + (size_t)(hh * 64 + rv1) * TSEQ + jv1 * 8;

#define STAGE(buf, k0) do { \
        gload_lds16(gk0 + (size_t)(k0) * 3072, Klds[buf] + cK0 * 8); \
        gload_lds16(gk1 + (size_t)(k0) * 3072, Klds[buf] + cK1 * 8); \
        gload_lds16(gv0 + (k0), Vlds[buf] + cK0 * 8); \
        gload_lds16(gv1 + (k0), Vlds[buf] + cK1 * 8); \
    } while (0)

    const int nIter = (65 - ii) >> 1;
    STAGE(0, 0);

    int cur = 0;
    for (int j = 0; j < nIter; j++) {
        __syncthreads();   // drains stage(j); all waves done reading buf[cur^1]
        if (j + 1 < nIter) STAGE(cur ^ 1, (j + 1) * 128);

        const int kt = 2 * j + grp;
        const bool aB = kt < ntB;
        const bool aA = kt <= ii;
        if (aB | aA) {
            const u16* Kl = Klds[cur] + grp * (64 * 64);
            const u16* Vl = Vlds[cur];
            const int klim = wv * 16 + fr;

            // S^T frags: st[ct][r] = S[k_local=ct*16+g*4+r][q=qw+fr]
            f32x4 stA[4] = {zero4, zero4, zero4, zero4};
            f32x4 stB[4] = {zero4, zero4, zero4, zero4};
#pragma unroll
            for (int ct = 0; ct < 4; ct++) {
#pragma unroll
                for (int ds = 0; ds < 2; ds++) {
                    const bf16x8 bk = *(const bf16x8*)(Kl + (ct * 16 + fr) * 64 + (((ds * 4 + g) ^ (fr & 7)) * 8));
                    if (aB) stB[ct] = __builtin_amdgcn_mfma_f32_16x16x32_bf16(bk, aqB[ds], stB[ct], 0, 0, 0);
                    if (aA) stA[ct] = __builtin_amdgcn_mfma_f32_16x16x32_bf16(bk, aqA[ds], stA[ct], 0, 0, 0);
                }
            }

            if (aB) {
                softmax_update(stB, kt == ntB - 1, klim, g, fr, mB, lB, oB, Plds[w]);
                __builtin_amdgcn_s_waitcnt(0xc07f);   // lgkmcnt(0): own P writes visible
#pragma unroll
                for (int kkh = 0; kkh < 2; kkh++) {
                    const bf16x8 pa = *(const bf16x8*)(&Plds[w][fr * 64 + (((kkh * 4 + g) ^ (fr & 7)) * 8)]);
#pragma unroll
                    for (int dt = 0; dt < 4; dt++) {
                        const int cc = grp * 8 + kkh * 4 + g;
                        const bf16x8 bv = *(const bf16x8*)(Vl + (dt * 16 + fr) * 128 + (((cc & 8) | ((cc & 7) ^ (fr & 7))) * 8));
                        oB[dt] = __builtin_amdgcn_mfma_f32_16x16x32_bf16(pa, bv, oB[dt], 0, 0, 0);
                    }
                }
            }
            if (aA) {
                softmax_update(stA, kt == ii, klim, g, fr, mA, lA, oA, Plds[w]);
                __builtin_amdgcn_s_waitcnt(0xc07f);
#pragma unroll
                for (int kkh = 0; kkh < 2; kkh++) {
                    const bf16x8 pa = *(const bf16x8*)(&Plds[w][fr * 64 + (((kkh * 4 + g) ^ (fr & 7)) * 8)]);
#pragma unroll
                    for (int dt = 0; dt < 4; dt++) {
                        const int cc = grp * 8 + kkh * 4 + g;
                        const bf16x8 bv = *(const bf16x8*)(Vl + (dt * 16 + fr) * 128 + (((cc & 8) | ((cc & 7) ^ (fr & 7))) * 8));
                        oA[dt] = __builtin_amdgcn_mfma_f32_16x16x32_bf16(pa, bv, oA[dt], 0, 0, 0);
                    }
                }
            }
        }
        cur ^= 1;
    }
#undef STAGE

    // ---- split-K merge: group1 -> LDS, group0 merges + writes ----
    __syncthreads();                      // all staging/compute done; reuse K/V LDS
    float* Of = (float*)&Klds[0][0];      // [wv][s][16q][64d] f32 = 32KB
    float2* Ml = (float2*)&Vlds[0][0];    // [wv][s][16q] {m,l}
    const float C = 0.125f * 1.4426950408889634f;
    if (grp == 1) {
#pragma unroll
        for (int dt = 0; dt < 4; dt++)
#pragma unroll
            for (int jq = 0; jq < 4; jq++) {
                Of[((wv * 2 + 0) * 16 + g * 4 + jq) * 64 + dt * 16 + fr] = oA[dt][jq];
                Of[((wv * 2 + 1) * 16 + g * 4 + jq) * 64 + dt * 16 + fr] = oB[dt][jq];
            }
        if (g == 0) {
            Ml[(wv * 2 + 0) * 16 + fr] = make_float2(mA, lA);
            Ml[(wv * 2 + 1) * 16 + fr] = make_float2(mB, lB);
        }
    }
    __syncthreads();
    if (grp == 0) {
#pragma unroll
        for (int jq = 0; jq < 4; jq++) {
            // tile A
            {
                const float m0 = __shfl(mA, g * 4 + jq), l0 = __shfl(lA, g * 4 + jq);
                const float2 ml1 = Ml[(wv * 2 + 0) * 16 + g * 4 + jq];
                const float mm = fmaxf(m0, ml1.x);
                const float s0 = exp2_hw((m0 - mm) * C);
                const float s1 = exp2_hw((ml1.x - mm) * C);
                const float rl = rcp_hw(__builtin_fmaf(l0, s0, ml1.y * s1));
#pragma unroll
                for (int dt = 0; dt < 4; dt++) {
                    const float o1 = Of[((wv * 2 + 0) * 16 + g * 4 + jq) * 64 + dt * 16 + fr];
                    y[(size_t)(qAw + g * 4 + jq) * DMODEL + hh * 64 + dt * 16 + fr] =
                        f2bf((oA[dt][jq] * s0 + o1 * s1) * rl);
                }
            }
            // tile B
            {
                const float m0 = __shfl(mB, g * 4 + jq), l0 = __shfl(lB, g * 4 + jq);
                const float2 ml1 = Ml[(wv * 2 + 1) * 16 + g * 4 + jq];
                const float mm = fmaxf(m0, ml1.x);
                const float s0 = exp2_hw((m0 - mm) * C);
                const float s1 = exp2_hw((ml1.x - mm) * C);
                const float rl = rcp_hw(__builtin_fmaf(l0, s0, ml1.y * s1));
#pragma unroll
                for (int dt = 0; dt < 4; dt++) {
                    const float o1 = Of[((wv * 2 + 1) * 16 + g * 4 + jq) * 64 + dt * 16 + fr];
                    y[(size_t)(qBw + g * 4 + jq) * DMODEL + hh * 64 + dt * 16 + fr] =
                        f2bf((oB[dt][jq] * s0 + o1 * s1) * rl);
                }
            }
        }
    }
}

extern "C" void kernel_launch(void* const* d_in, const int* in_sizes, int n_in,
                              void* d_out, int out_size, void* d_ws, size_t ws_size,
                              hipStream_t stream)
{
    const float* x      = (const float*)d_in[0];
    const float* ln1_s  = (const float*)d_in[1];
    const float* ln1_b  = (const float*)d_in[2];
    const float* W_attn = (const float*)d_in[3];
    const float* b_attn = (const float*)d_in[4];
    const float* W_proj = (const float*)d_in[5];
    const float* b_proj = (const float*)d_in[6];
    const float* ln2_s  = (const float*)d_in[7];
    const float* ln2_b  = (const float*)d_in[8];
    const float* W_fc   = (const float*)d_in[9];
    const float* b_fc   = (const float*)d_in[10];
    const float* W_fc2  = (const float*)d_in[11];
    const float* b_fc2  = (const float*)d_in[12];
    float* out = (float*)d_out;

    char* ws = (char*)d_ws;
    u16* WtAttn = (u16*)ws; ws += (size_t)3072 * 1024 * 2;
    u16* WtProj = (u16*)ws; ws += (size_t)1024 * 1024 * 2;
    u16* WtFc   = (u16*)ws; ws += (size_t)4096 * 1024 * 2;
    u16* WtFc2  = (u16*)ws; ws += (size_t)1024 * 4096 * 2;
    u16* bufA   = (u16*)ws; ws += (size_t)4096 * 1024 * 2;  // h / y / h2
    u16* bufB   = (u16*)ws; ws += (size_t)4096 * 4096 * 2;  // qkv / m
    float* x1   = (float*)ws; ws += (size_t)4096 * 1024 * 4;
    u16* Vtg    = (u16*)x1;      // alias: x1 not live until proj GEMM; Vt dead by then
    float* P0   = (float*)d_ws;  // FC2 partial: overlays WtAttn+WtProj+WtFc (dead then)

    // fused prep: 4 weight transposes + ln1 (all independent), one launch
    prep_kernel<<<4096, 256, 0, stream>>>(x, ln1_s, ln1_b, bufA,
                                          W_attn, WtAttn, W_proj, WtProj,
                                          W_fc, WtFc, W_fc2, WtFc2);

    // attention branch
    gemm_kernel<128, 0, 1, 0, 1><<<dim3(24, 32, 1), 256, 0, stream>>>(
        bufA, 1024, WtAttn, 1024, b_attn, nullptr, bufB, nullptr, nullptr, 4096, 3072, 1024);
    v_transpose_kernel<<<dim3(TSEQ / 64, NHEAD), 256, 0, stream>>>(bufB, Vtg);
    attn_kernel<<<dim3(32, NHEAD), 512, 0, stream>>>(bufB, Vtg, bufA);
    gemm_kernel<64, 0, 0, 1, 1><<<dim3(16, 32, 1), 256, 0, stream>>>(
        bufA, 1024, WtProj, 1024, b_proj, x, nullptr, x1, nullptr, 4096, 1024, 1024);

    // MLP branch
    ln_kernel<<<TSEQ / 4, 256, 0, stream>>>(x1, ln2_s, ln2_b, bufA);
    gemm256_kernel<<<dim3(32, 16), 512, 0, stream>>>(
        bufA, WtFc, b_fc, bufB, 4096, 4096, 1024);
    // FC2 split-K=2: z=0 -> P0 partial; z=1 -> out with x1 + b_fc2 fused (FUSE_Z1)
    gemm_kernel<128, 0, 0, 0, 0, 1><<<dim3(8, 32, 2), 256, 0, stream>>>(
        bufB, 4096, WtFc2, 4096, b_fc2, x1, nullptr, P0, out, 4096, 1024, 2048);
    fc2_merge_kernel<<<4096, 256, 0, stream>>>(out, P0);
}

// Round 18
// 271.531 us; speedup vs baseline: 1.3383x; 1.0157x over previous
//
#include <hip/hip_runtime.h>
#include <hip/hip_bf16.h>

typedef short bf16x8 __attribute__((ext_vector_type(8)));
typedef float f32x4 __attribute__((ext_vector_type(4)));
typedef unsigned short u16;
typedef unsigned int u32;

// dims (fixed per problem)
#define TSEQ 4096
#define DMODEL 1024
#define NHEAD 16
#define DHEAD 64
#define DFF 4096

__device__ __forceinline__ u16 f2bf(float f) {
    u32 u = __builtin_bit_cast(u32, f);
    u32 lsb = (u >> 16) & 1u;
    u += 0x7fffu + lsb;
    return (u16)(u >> 16);
}

__device__ __forceinline__ float exp2_hw(float x) {   // 2^x
    float r;
    asm("v_exp_f32 %0, %1" : "=v"(r) : "v"(x));
    return r;
}

__device__ __forceinline__ float rcp_hw(float x) {    // 1/x (approx, ~1ulp)
    float r;
    asm("v_rcp_f32 %0, %1" : "=v"(r) : "v"(x));
    return r;
}

__device__ __forceinline__ u32 cvt_pk_bf16(float a, float b) {  // lo=bf16(a), hi=bf16(b)
    u32 r;
    asm("v_cvt_pk_bf16_f32 %0, %1, %2" : "=v"(r) : "v"(a), "v"(b));
    return r;
}

__device__ __forceinline__ void gload_lds16(const u16* g, u16* l) {
    __builtin_amdgcn_global_load_lds(
        (const __attribute__((address_space(1))) u32*)g,
        (__attribute__((address_space(3))) u32*)l, 16, 0, 0);
}

// T1 XCD swizzle (m157/m204): same-row-panel blocks -> same XCD's L2.
// Requires gridDim.x*gridDim.y % 8 == 0 (all our GEMM grids qualify).
__device__ __forceinline__ void xcd_swizzle(int& bx, int& by) {
    const int gx = gridDim.x;
    const int nwg = gx * gridDim.y;
    const int flat = by * gx + bx;
    const int q = nwg >> 3;
    const int swz = (flat & 7) * q + (flat >> 3);
    bx = swz % gx;
    by = swz / gx;
}

// ---------------- fused prep: 4x weight transpose+cast AND ln1, one launch ----------
__device__ __forceinline__ void transpose_tile(
    const float* __restrict__ W, u16* __restrict__ Wt, int K, int N, int bx, int by,
    float (*tile)[65])
{
    const int t = threadIdx.x;
    const int c = t & 63, r4 = t >> 6;
    const int col0 = bx * 64;  // N dim
    const int row0 = by * 64;  // K dim
#pragma unroll
    for (int p = 0; p < 16; p++) {
        const int r = 4 * p + r4;
        tile[r][c] = W[(size_t)(row0 + r) * N + col0 + c];
    }
    __syncthreads();
#pragma unroll
    for (int p = 0; p < 16; p++) {
        const int r = 4 * p + r4;
        Wt[(size_t)(col0 + r) * K + row0 + c] = f2bf(tile[c][r]);
    }
}

__device__ __forceinline__ void ln_rows(
    const float* __restrict__ x, const float* __restrict__ sc,
    const float* __restrict__ bi, u16* __restrict__ out, int blk)
{
    const int lane = threadIdx.x & 63;
    const int row = blk * 4 + (threadIdx.x >> 6);
    const float* xr = x + (size_t)row * DMODEL;
    float4 v[4];
    float s = 0.f, s2 = 0.f;
#pragma unroll
    for (int q = 0; q < 4; q++) {
        v[q] = *(const float4*)(xr + 4 * (lane + 64 * q));
        s  += v[q].x + v[q].y + v[q].z + v[q].w;
        s2 += v[q].x * v[q].x + v[q].y * v[q].y + v[q].z * v[q].z + v[q].w * v[q].w;
    }
#pragma unroll
    for (int off = 1; off < 64; off <<= 1) {
        s  += __shfl_xor(s, off);
        s2 += __shfl_xor(s2, off);
    }
    const float mu = s * (1.f / DMODEL);
    const float rstd = rsqrtf(s2 * (1.f / DMODEL) - mu * mu + 1e-5f);
#pragma unroll
    for (int q = 0; q < 4; q++) {
        const int c = 4 * (lane + 64 * q);
        const float4 scv = *(const float4*)(sc + c);
        const float4 biv = *(const float4*)(bi + c);
        ushort4 ov;
        ov.x = f2bf((v[q].x - mu) * rstd * scv.x + biv.x);
        ov.y = f2bf((v[q].y - mu) * rstd * scv.y + biv.y);
        ov.z = f2bf((v[q].z - mu) * rstd * scv.z + biv.z);
        ov.w = f2bf((v[q].w - mu) * rstd * scv.w + biv.w);
        *(ushort4*)(out + (size_t)row * DMODEL + c) = ov;
    }
}

__global__ __launch_bounds__(256)
void prep_kernel(const float* __restrict__ x, const float* __restrict__ ln1_s,
                 const float* __restrict__ ln1_b, u16* __restrict__ h,
                 const float* __restrict__ W_attn, u16* __restrict__ WtAttn,
                 const float* __restrict__ W_proj, u16* __restrict__ WtProj,
                 const float* __restrict__ W_fc,   u16* __restrict__ WtFc,
                 const float* __restrict__ W_fc2,  u16* __restrict__ WtFc2)
{
    __shared__ float tile[64][65];
    int b = blockIdx.x;
    if (b < 1024) { ln_rows(x, ln1_s, ln1_b, h, b); return; }
    b -= 1024;
    if (b < 768)  { transpose_tile(W_attn, WtAttn, 1024, 3072, b % 48, b / 48, tile); return; }
    b -= 768;
    if (b < 256)  { transpose_tile(W_proj, WtProj, 1024, 1024, b % 16, b / 16, tile); return; }
    b -= 256;
    if (b < 1024) { transpose_tile(W_fc,   WtFc,   1024, 4096, b % 64, b / 64, tile); return; }
    b -= 1024;
    transpose_tile(W_fc2, WtFc2, 4096, 1024, b % 16, b / 16, tile);
}

// ---------------- layernorm: f32 [T,1024] -> bf16 [T,1024] ----------------
__global__ __launch_bounds__(256)
void ln_kernel(const float* __restrict__ x, const float* __restrict__ sc,
               const float* __restrict__ bi, u16* __restrict__ out)
{
    ln_rows(x, sc, bi, out, blockIdx.x);
}

// ---------------- QKV GEMM with fused V-transpose ------------------------------------
// C[4096,3072] = h * WtAttn^T + b_attn. Q,K tiles (n0 < 2048) -> qkv[T,3072] as
// before; V tiles (n0 >= 2048, block-uniform since 2048 = 16*128) write DIRECTLY to
// Vt[h*64+d][T]: per (i,j) the 4 acc rows are 4 consecutive T -> one packed 8B store.
// Replaces the separate v_transpose kernel (-64MB traffic, -1 launch); qkv's V region
// is never written (nothing reads it).
__global__ __launch_bounds__(256)
void gemm_qkv_kernel(const u16* __restrict__ A, const u16* __restrict__ Bt,
                     const float* __restrict__ bias, u16* __restrict__ outb,
                     u16* __restrict__ Vt)
{
    constexpr int K = 1024, N = 3072;
    __shared__ u16 Alds[128 * 64];
    __shared__ u16 Blds[128 * 64];
    const int t = threadIdx.x;
    const int lane = t & 63, w = t >> 6;
    const int g = lane >> 4, fr = lane & 15;
    int bx = blockIdx.x, by = blockIdx.y;
    xcd_swizzle(bx, by);                       // T1: L2 locality
    const int m0 = by * 128, n0 = bx * 128;
    const int rowbase = (w >> 1) * 64;
    const int colbase = (w & 1) * 64;

    f32x4 zero4 = {0.f, 0.f, 0.f, 0.f};
    f32x4 acc[4][4];
#pragma unroll
    for (int i = 0; i < 4; i++)
#pragma unroll
        for (int j = 0; j < 4; j++) acc[i][j] = zero4;

    for (int k0 = 0; k0 < K; k0 += 64) {
        __syncthreads();
#pragma unroll
        for (int p = 0; p < 4; p++) {            // A tile: 128x64 = 1024 chunks
            const int c = p * 256 + t;
            const int r = c >> 3, j = (c & 7) ^ (r & 7);
            gload_lds16(A + (size_t)(m0 + r) * K + k0 + j * 8, Alds + c * 8);
        }
#pragma unroll
        for (int p = 0; p < 4; p++) {            // B tile: 128x64 = 1024 chunks
            const int c = p * 256 + t;
            const int r = c >> 3, j = (c & 7) ^ (r & 7);
            gload_lds16(Bt + (size_t)(n0 + r) * K + k0 + j * 8, Blds + c * 8);
        }
        __syncthreads();

#pragma unroll
        for (int ks = 0; ks < 2; ks++) {
            bf16x8 af[4], bfr[4];
#pragma unroll
            for (int i = 0; i < 4; i++)
                af[i] = *(const bf16x8*)(Alds + (rowbase + i * 16 + fr) * 64 + (((ks * 4 + g) ^ (fr & 7)) * 8));
#pragma unroll
            for (int j = 0; j < 4; j++)
                bfr[j] = *(const bf16x8*)(Blds + (colbase + j * 16 + fr) * 64 + (((ks * 4 + g) ^ (fr & 7)) * 8));
#pragma unroll
            for (int i = 0; i < 4; i++)
#pragma unroll
                for (int j = 0; j < 4; j++)
                    acc[i][j] = __builtin_amdgcn_mfma_f32_16x16x32_bf16(af[i], bfr[j], acc[i][j], 0, 0, 0);
        }
    }

    if (n0 >= 2048) {
        // V tile: write transposed, packed 8B per (i,j)
#pragma unroll
        for (int j = 0; j < 4; j++) {
            const int col = n0 + colbase + j * 16 + fr;
            const float bv = bias[col];
            const int vrow = col - 2048;         // = h*64 + d
#pragma unroll
            for (int i = 0; i < 4; i++) {
                const int trow = m0 + rowbase + i * 16 + g * 4;
                uint2 pk;
                pk.x = cvt_pk_bf16(acc[i][j][0] + bv, acc[i][j][1] + bv);
                pk.y = cvt_pk_bf16(acc[i][j][2] + bv, acc[i][j][3] + bv);
                *(uint2*)(Vt + (size_t)vrow * TSEQ + trow) = pk;
            }
        }
    } else {
#pragma unroll
        for (int j = 0; j < 4; j++) {
            const int col = n0 + colbase + j * 16 + fr;
            const float bv = bias[col];
#pragma unroll
            for (int i = 0; i < 4; i++) {
#pragma unroll
                for (int r = 0; r < 4; r++) {
                    const int row = m0 + rowbase + i * 16 + g * 4 + r;
                    outb[(size_t)row * N + col] = f2bf(acc[i][j][r] + bv);
                }
            }
        }
    }
}

// ---------------- GEMM: C[M,N] = A[M,K](bf16) * Bt[N,K](bf16)^T [+bias][+gelu][+res] --
// BM=128, BK=64, XOR-swizzled LDS (T2/m173). Split-K via gridDim.z; FUSE_Z1: z==1
// partial additionally adds res + bias (final merge only adds the z0 part).
template<int BN, int GELU_F, int OUT_BF16, int HAS_RES, int HAS_BIAS, int FUSE_Z1 = 0>
__global__ __launch_bounds__(256)
void gemm_kernel(const u16* __restrict__ A, int lda,
                 const u16* __restrict__ Bt, int ldb,
                 const float* __restrict__ bias, const float* __restrict__ res,
                 u16* __restrict__ outb, float* __restrict__ outf0,
                 float* __restrict__ outf1, int M, int N, int Kblk)
{
    constexpr int MI = (BN == 128) ? 4 : 2;
    __shared__ u16 Alds[128 * 64];
    __shared__ u16 Blds[BN * 64];
    const int t = threadIdx.x;
    const int lane = t & 63, w = t >> 6;
    const int g = lane >> 4, fr = lane & 15;
    int bx = blockIdx.x, by = blockIdx.y;
    xcd_swizzle(bx, by);                       // T1: L2 locality
    const int m0 = by * 128, n0 = bx * BN;
    const size_t koff = (size_t)blockIdx.z * Kblk;
    const int rowbase = (BN == 128) ? (w >> 1) * 64 : w * 32;
    const int colbase = (BN == 128) ? (w & 1) * 64 : 0;
    float* outf = blockIdx.z ? outf1 : outf0;

    f32x4 zero4 = {0.f, 0.f, 0.f, 0.f};
    f32x4 acc[MI][4];
#pragma unroll
    for (int i = 0; i < MI; i++)
#pragma unroll
        for (int j = 0; j < 4; j++) acc[i][j] = zero4;

    for (int k0 = 0; k0 < Kblk; k0 += 64) {
        __syncthreads();
#pragma unroll
        for (int p = 0; p < 4; p++) {            // A tile: 128x64 = 1024 chunks
            const int c = p * 256 + t;
            const int r = c >> 3, j = (c & 7) ^ (r & 7);
            gload_lds16(A + (size_t)(m0 + r) * lda + koff + k0 + j * 8, Alds + c * 8);
        }
#pragma unroll
        for (int p = 0; p < (BN == 128 ? 4 : 2); p++) {  // B tile: BNx64 chunks
            const int c = p * 256 + t;
            const int r = c >> 3, j = (c & 7) ^ (r & 7);
            gload_lds16(Bt + (size_t)(n0 + r) * ldb + koff + k0 + j * 8, Blds + c * 8);
        }
        __syncthreads();

#pragma unroll
        for (int ks = 0; ks < 2; ks++) {
            bf16x8 af[MI], bfr[4];
#pragma unroll
            for (int i = 0; i < MI; i++)
                af[i] = *(const bf16x8*)(Alds + (rowbase + i * 16 + fr) * 64 + (((ks * 4 + g) ^ (fr & 7)) * 8));
#pragma unroll
            for (int j = 0; j < 4; j++)
                bfr[j] = *(const bf16x8*)(Blds + (colbase + j * 16 + fr) * 64 + (((ks * 4 + g) ^ (fr & 7)) * 8));
#pragma unroll
            for (int i = 0; i < MI; i++)
#pragma unroll
                for (int j = 0; j < 4; j++)
                    acc[i][j] = __builtin_amdgcn_mfma_f32_16x16x32_bf16(af[i], bfr[j], acc[i][j], 0, 0, 0);
        }
    }

    const bool fuse = FUSE_Z1 && (blockIdx.z == 1);
#pragma unroll
    for (int j = 0; j < 4; j++) {
        const int col = n0 + colbase + j * 16 + fr;
        float bv = 0.f;
        if (HAS_BIAS) bv = bias[col];
        if (FUSE_Z1 && fuse) bv = bias[col];
#pragma unroll
        for (int i = 0; i < MI; i++) {
#pragma unroll
            for (int r = 0; r < 4; r++) {
                const int row = m0 + rowbase + i * 16 + g * 4 + r;
                float v = acc[i][j][r] + bv;
                if (GELU_F) {
                    const float q = 0.7978845608028654f * (v + 0.044715f * v * v * v);
                    const float e = exp2_hw(fminf(q, 30.f) * 2.8853900817779268f);
                    v = v * e * rcp_hw(e + 1.0f);
                }
                if (HAS_RES) v += res[(size_t)row * N + col];
                if (FUSE_Z1 && fuse) v += res[(size_t)row * N + col];
                if (OUT_BF16) outb[(size_t)row * N + col] = f2bf(v);
                else          outf[(size_t)row * N + col] = v;
            }
        }
    }
}

// ---------------- GEMM 256x128 (8 waves): C = A*Bt^T + bias, gelu, bf16 out ---------
__global__ __launch_bounds__(512, 2)
void gemm256_kernel(const u16* __restrict__ A, const u16* __restrict__ Bt,
                    const float* __restrict__ bias, u16* __restrict__ outb,
                    int M, int N, int K)
{
    __shared__ u16 Alds[256 * 64];   // 32KB
    __shared__ u16 Blds[128 * 64];   // 16KB
    const int t = threadIdx.x;
    const int lane = t & 63, w = t >> 6;
    const int g = lane >> 4, fr = lane & 15;
    int bx = blockIdx.x, by = blockIdx.y;
    xcd_swizzle(bx, by);                       // T1: L2 locality
    const int m0 = by * 256, n0 = bx * 128;
    const int rowbase = (w >> 1) * 64;
    const int colbase = (w & 1) * 64;

    f32x4 zero4 = {0.f, 0.f, 0.f, 0.f};
    f32x4 acc[4][4];
#pragma unroll
    for (int i = 0; i < 4; i++)
#pragma unroll
        for (int j = 0; j < 4; j++) acc[i][j] = zero4;

    for (int k0 = 0; k0 < K; k0 += 64) {
        __syncthreads();
#pragma unroll
        for (int p = 0; p < 4; p++) {            // A tile: 256x64 = 2048 chunks
            const int c = p * 512 + t;
            const int r = c >> 3, j = (c & 7) ^ (r & 7);
            gload_lds16(A + (size_t)(m0 + r) * K + k0 + j * 8, Alds + c * 8);
        }
#pragma unroll
        for (int p = 0; p < 2; p++) {            // B tile: 128x64 = 1024 chunks
            const int c = p * 512 + t;
            const int r = c >> 3, j = (c & 7) ^ (r & 7);
            gload_lds16(Bt + (size_t)(n0 + r) * K + k0 + j * 8, Blds + c * 8);
        }
        __syncthreads();

#pragma unroll
        for (int ks = 0; ks < 2; ks++) {
            bf16x8 af[4], bfr[4];
#pragma unroll
            for (int i = 0; i < 4; i++)
                af[i] = *(const bf16x8*)(Alds + (rowbase + i * 16 + fr) * 64 + (((ks * 4 + g) ^ (fr & 7)) * 8));
#pragma unroll
            for (int j = 0; j < 4; j++)
                bfr[j] = *(const bf16x8*)(Blds + (colbase + j * 16 + fr) * 64 + (((ks * 4 + g) ^ (fr & 7)) * 8));
#pragma unroll
            for (int i = 0; i < 4; i++)
#pragma unroll
                for (int j = 0; j < 4; j++)
                    acc[i][j] = __builtin_amdgcn_mfma_f32_16x16x32_bf16(af[i], bfr[j], acc[i][j], 0, 0, 0);
        }
    }

#pragma unroll
    for (int j = 0; j < 4; j++) {
        const int col = n0 + colbase + j * 16 + fr;
        const float bv = bias[col];
#pragma unroll
        for (int i = 0; i < 4; i++) {
#pragma unroll
            for (int r = 0; r < 4; r++) {
                const int row = m0 + rowbase + i * 16 + g * 4 + r;
                float v = acc[i][j][r] + bv;
                const float q = 0.7978845608028654f * (v + 0.044715f * v * v * v);
                const float e = exp2_hw(fminf(q, 30.f) * 2.8853900817779268f);
                v = v * e * rcp_hw(e + 1.0f);
                outb[(size_t)row * N + col] = f2bf(v);
            }
        }
    }
}

// ---------------- FC2 merge: out += part(z0) ----------------------------------------
__global__ __launch_bounds__(256)
void fc2_merge_kernel(float* __restrict__ out, const float* __restrict__ part)
{
    const int i = blockIdx.x * 256 + threadIdx.x;
    const float4 o = ((const float4*)out)[i];
    const float4 p = ((const float4*)part)[i];
    float4 v;
    v.x = o.x + p.x;
    v.y = o.y + p.y;
    v.z = o.z + p.z;
    v.w = o.w + p.w;
    ((float4*)out)[i] = v;
}

// -------- attn helper: in-lane online softmax (raw S units) + P pack/write ----------
// p = exp(0.125*(s - m)) = 2^(s*C - m*C), C = 0.125*log2(e). Defer-max: keep old m
// while vm <= m + 64 (== 8 scaled); skip O-rescale when all rows deferred.
// FROZEN (R14/R16 lessons): masking stays inline, no setprio, bounds (512,4).
// Any change that grows VGPR past 64 either spills (R14, at cap 64) or halves
// resident waves (R16, VGPR 112 at cap 128): both ~2-7x slowdowns.
__device__ __forceinline__ void softmax_update(
    const f32x4 st[4], bool diag, int klim, int g, int fr,
    float& mrow, float& lrow, f32x4 o[4], u16* Pl)
{
    const float ninf = -__builtin_inff();
    const float C = 0.125f * 1.4426950408889634f;
    float av[4][4];
#pragma unroll
    for (int ct = 0; ct < 4; ct++)
#pragma unroll
        for (int r = 0; r < 4; r++) {
            float aa = st[ct][r];
            if (diag && (ct * 16 + g * 4 + r) > klim) aa = ninf;
            av[ct][r] = aa;
        }
    float m0 = fmaxf(fmaxf(av[0][0], av[0][1]), fmaxf(av[0][2], av[0][3]));
    float m1 = fmaxf(fmaxf(av[1][0], av[1][1]), fmaxf(av[1][2], av[1][3]));
    float m2 = fmaxf(fmaxf(av[2][0], av[2][1]), fmaxf(av[2][2], av[2][3]));
    float m3 = fmaxf(fmaxf(av[3][0], av[3][1]), fmaxf(av[3][2], av[3][3]));
    float vm = fmaxf(fmaxf(m0, m1), fmaxf(m2, m3));
    vm = fmaxf(vm, __shfl_xor(vm, 16));
    vm = fmaxf(vm, __shfl_xor(vm, 32));
    const float mn = (vm <= mrow + 64.f) ? mrow : vm;   // defer-max (T13)
    const float mnC = mn * C;
    float rs = 0.f;
#pragma unroll
    for (int ct = 0; ct < 4; ct++) {
        const float p0 = exp2_hw(__builtin_fmaf(av[ct][0], C, -mnC));
        const float p1 = exp2_hw(__builtin_fmaf(av[ct][1], C, -mnC));
        const float p2 = exp2_hw(__builtin_fmaf(av[ct][2], C, -mnC));
        const float p3 = exp2_hw(__builtin_fmaf(av[ct][3], C, -mnC));
        rs += (p0 + p1) + (p2 + p3);
        uint2 pk;
        pk.x = cvt_pk_bf16(p0, p1);
        pk.y = cvt_pk_bf16(p2, p3);
        const int chunk = ct * 2 + (g >> 1);
        const int addr = fr * 64 + ((chunk ^ (fr & 7)) * 8) + (g & 1) * 4;
        *(uint2*)(Pl + addr) = pk;
    }
    rs += __shfl_xor(rs, 16);
    rs += __shfl_xor(rs, 32);
    const float sc = exp2_hw((mrow - mn) * C);          // ==1 when deferred
    lrow = __builtin_fmaf(lrow, sc, rs);
    const bool nores = (mn == mrow);
    mrow = mn;
    if (!__all(nores)) {
        float scb[4];
#pragma unroll
        for (int j = 0; j < 4; j++) scb[j] = __shfl(sc, g * 4 + j);
#pragma unroll
        for (int dt = 0; dt < 4; dt++)
#pragma unroll
            for (int j = 0; j < 4; j++) o[dt][j] *= scb[j];
    }
}

// ---------------- causal flash attention, paired q-tiles + split-K, 8 waves --------
// EXACTLY the R12 body (89.4us, VGPR 64, no spill). FROZEN — see softmax_update note.
__global__ __launch_bounds__(512, 4)
void attn_kernel(const u16* __restrict__ qkv, const u16* __restrict__ Vtg,
                 u16* __restrict__ y)
{
    __shared__ u16 Klds[2][128 * 64];   // [k=128][d=64]
    __shared__ u16 Vlds[2][64 * 128];   // [d=64][k=128]
    __shared__ u16 Plds[8][16 * 64];
    const int t = threadIdx.x, lane = t & 63, w = t >> 6;
    const int g = lane >> 4, fr = lane & 15;
    const int wv = w & 3, grp = w >> 2;
    const int hh = blockIdx.y;
    const int ii = blockIdx.x;                 // pair (ii, 63-ii)
    const int ntB = 64 - ii;
    const int qAw = ii * 64 + wv * 16;
    const int qBw = (63 - ii) * 64 + wv * 16;

    // Q fragments: lane (g,fr) holds Q[qw+fr][d = ds*32 + g*8 + i]
    bf16x8 aqA[2], aqB[2];
#pragma unroll
    for (int s = 0; s < 2; s++) {
        aqA[s] = *(const bf16x8*)(qkv + (size_t)(qAw + fr) * 3072 + hh * 64 + s * 32 + g * 8);
        aqB[s] = *(const bf16x8*)(qkv + (size_t)(qBw + fr) * 3072 + hh * 64 + s * 32 + g * 8);
    }

    f32x4 zero4 = {0.f, 0.f, 0.f, 0.f};
    f32x4 oA[4] = {zero4, zero4, zero4, zero4};
    f32x4 oB[4] = {zero4, zero4, zero4, zero4};
    const float ninf = -__builtin_inff();
    float mA = ninf, lA = 0.f, mB = ninf, lB = 0.f;

    // staging: K tile [k=128][d=64] as 1024 chunks [r=c>>3][j], V tile [d=64][k=128]
    // as 1024 chunks [d=c>>4][cj]; dest linear, src XOR-swizzled (grp-half bit kept).
    const int cK0 = t, cK1 = t + 512;
    const int rK0 = cK0 >> 3, jK0 = (cK0 & 7) ^ (rK0 & 7);
    const int rK1 = cK1 >> 3, jK1 = (cK1 & 7) ^ (rK1 & 7);
    const int rv0 = cK0 >> 4, cj0 = cK0 & 15;
    const int jv0 = (cj0 & 8) | ((cj0 & 7) ^ (rv0 & 7));
    const int rv1 = cK1 >> 4, cj1 = cK1 & 15;
    const int jv1 = (cj1 & 8) | ((cj1 & 7) ^ (rv1 & 7));
    const u16* gk0 = qkv + (size_t)rK0 * 3072 + 1024 + hh * 64 + jK0 * 8;
    const u16* gk1 = qkv + (size_t)rK1 * 3072 + 1024 + hh * 64 + jK1 * 8;
    const u16* gv0 = Vtg + (size_t)(hh * 64 + rv0) * TSEQ + jv0 * 8;
    const u16* gv1 = Vtg + (size_t)(hh * 64 + rv1) * TSEQ + jv1 * 8;

#define STAGE(buf, k0) do { \
        gload_lds16(gk0 + (size_t)(k0) * 3072, Klds[buf] + cK0 * 8); \
        gload_lds16(gk1 + (size_t)(k0) * 3072, Klds[buf] + cK1 * 8); \
        gload_lds16(gv0 + (k0), Vlds[buf] + cK0 * 8); \
        gload_lds16(gv1 + (k0), Vlds[buf] + cK1 * 8); \
    } while (0)

    const int nIter = (65 - ii) >> 1;
    STAGE(0, 0);

    int cur = 0;
    for (int j = 0; j < nIter; j++) {
        __syncthreads();   // drains stage(j); all waves done reading buf[cur^1]
        if (j + 1 < nIter) STAGE(cur ^ 1, (j + 1) * 128);

        const int kt = 2 * j + grp;
        const bool aB = kt < ntB;
        const bool aA = kt <= ii;
        if (aB | aA) {
            const u16* Kl = Klds[cur] + grp * (64 * 64);
            const u16* Vl = Vlds[cur];
            const int klim = wv * 16 + fr;

            // S^T frags: st[ct][r] = S[k_local=ct*16+g*4+r][q=qw+fr]
            f32x4 stA[4] = {zero4, zero4, zero4, zero4};
            f32x4 stB[4] = {zero4, zero4, zero4, zero4};
#pragma unroll
            for (int ct = 0; ct < 4; ct++) {
#pragma unroll
                for (int ds = 0; ds < 2; ds++) {
                    const bf16x8 bk = *(const bf16x8*)(Kl + (ct * 16 + fr) * 64 + (((ds * 4 + g) ^ (fr & 7)) * 8));
                    if (aB) stB[ct] = __builtin_amdgcn_mfma_f32_16x16x32_bf16(bk, aqB[ds], stB[ct], 0, 0, 0);
                    if (aA) stA[ct] = __builtin_amdgcn_mfma_f32_16x16x32_bf16(bk, aqA[ds], stA[ct], 0, 0, 0);
                }
            }

            if (aB) {
                softmax_update(stB, kt == ntB - 1, klim, g, fr, mB, lB, oB, Plds[w]);
                __builtin_amdgcn_s_waitcnt(0xc07f);   // lgkmcnt(0): own P writes visible
#pragma unroll
                for (int kkh = 0; kkh < 2; kkh++) {
                    const bf16x8 pa = *(const bf16x8*)(&Plds[w][fr * 64 + (((kkh * 4 + g) ^ (fr & 7)) * 8)]);
#pragma unroll
                    for (int dt = 0; dt < 4; dt++) {
                        const int cc = grp * 8 + kkh * 4 + g;
                        const bf16x8 bv = *(const bf16x8*)(Vl + (dt * 16 + fr) * 128 + (((cc & 8) | ((cc & 7) ^ (fr & 7))) * 8));
                        oB[dt] = __builtin_amdgcn_mfma_f32_16x16x32_bf16(pa, bv, oB[dt], 0, 0, 0);
                    }
                }
            }
            if (aA) {
                softmax_update(stA, kt == ii, klim, g, fr, mA, lA, oA, Plds[w]);
                __builtin_amdgcn_s_waitcnt(0xc07f);
#pragma unroll
                for (int kkh = 0; kkh < 2; kkh++) {
                    const bf16x8 pa = *(const bf16x8*)(&Plds[w][fr * 64 + (((kkh * 4 + g) ^ (fr & 7)) * 8)]);
#pragma unroll
                    for (int dt = 0; dt < 4; dt++) {
                        const int cc = grp * 8 + kkh * 4 + g;
                        const bf16x8 bv = *(const bf16x8*)(Vl + (dt * 16 + fr) * 128 + (((cc & 8) | ((cc & 7) ^ (fr & 7))) * 8));
                        oA[dt] = __builtin_amdgcn_mfma_f32_16x16x32_bf16(pa, bv, oA[dt], 0, 0, 0);
                    }
                }
            }
        }
        cur ^= 1;
    }
#undef STAGE

    // ---- split-K merge: group1 -> LDS, group0 merges + writes ----
    __syncthreads();                      // all staging/compute done; reuse K/V LDS
    float* Of = (float*)&Klds[0][0];      // [wv][s][16q][64d] f32 = 32KB
    float2* Ml = (float2*)&Vlds[0][0];    // [wv][s][16q] {m,l}
    const float C = 0.125f * 1.4426950408889634f;
    if (grp == 1) {
#pragma unroll
        for (int dt = 0; dt < 4; dt++)
#pragma unroll
            for (int jq = 0; jq < 4; jq++) {
                Of[((wv * 2 + 0) * 16 + g * 4 + jq) * 64 + dt * 16 + fr] = oA[dt][jq];
                Of[((wv * 2 + 1) * 16 + g * 4 + jq) * 64 + dt * 16 + fr] = oB[dt][jq];
            }
        if (g == 0) {
            Ml[(wv * 2 + 0) * 16 + fr] = make_float2(mA, lA);
            Ml[(wv * 2 + 1) * 16 + fr] = make_float2(mB, lB);
        }
    }
    __syncthreads();
    if (grp == 0) {
#pragma unroll
        for (int jq = 0; jq < 4; jq++) {
            // tile A
            {
                const float m0 = __shfl(mA, g * 4 + jq), l0 = __shfl(lA, g * 4 + jq);
                const float2 ml1 = Ml[(wv * 2 + 0) * 16 + g * 4 + jq];
                const float mm = fmaxf(m0, ml1.x);
                const float s0 = exp2_hw((m0 - mm) * C);
                const float s1 = exp2_hw((ml1.x - mm) * C);
                const float rl = rcp_hw(__builtin_fmaf(l0, s0, ml1.y * s1));
#pragma unroll
                for (int dt = 0; dt < 4; dt++) {
                    const float o1 = Of[((wv * 2 + 0) * 16 + g * 4 + jq) * 64 + dt * 16 + fr];
                    y[(size_t)(qAw + g * 4 + jq) * DMODEL + hh * 64 + dt * 16 + fr] =
                        f2bf((oA[dt][jq] * s0 + o1 * s1) * rl);
                }
            }
            // tile B
            {
                const float m0 = __shfl(mB, g * 4 + jq), l0 = __shfl(lB, g * 4 + jq);
                const float2 ml1 = Ml[(wv * 2 + 1) * 16 + g * 4 + jq];
                const float mm = fmaxf(m0, ml1.x);
                const float s0 = exp2_hw((m0 - mm) * C);
                const float s1 = exp2_hw((ml1.x - mm) * C);
                const float rl = rcp_hw(__builtin_fmaf(l0, s0, ml1.y * s1));
#pragma unroll
                for (int dt = 0; dt < 4; dt++) {
                    const float o1 = Of[((wv * 2 + 1) * 16 + g * 4 + jq) * 64 + dt * 16 + fr];
                    y[(size_t)(qBw + g * 4 + jq) * DMODEL + hh * 64 + dt * 16 + fr] =
                        f2bf((oB[dt][jq] * s0 + o1 * s1) * rl);
                }
            }
        }
    }
}

extern "C" void kernel_launch(void* const* d_in, const int* in_sizes, int n_in,
                              void* d_out, int out_size, void* d_ws, size_t ws_size,
                              hipStream_t stream)
{
    const float* x      = (const float*)d_in[0];
    const float* ln1_s  = (const float*)d_in[1];
    const float* ln1_b  = (const float*)d_in[2];
    const float* W_attn = (const float*)d_in[3];
    const float* b_attn = (const float*)d_in[4];
    const float* W_proj = (const float*)d_in[5];
    const float* b_proj = (const float*)d_in[6];
    const float* ln2_s  = (const float*)d_in[7];
    const float* ln2_b  = (const float*)d_in[8];
    const float* W_fc   = (const float*)d_in[9];
    const float* b_fc   = (const float*)d_in[10];
    const float* W_fc2  = (const float*)d_in[11];
    const float* b_fc2  = (const float*)d_in[12];
    float* out = (float*)d_out;

    char* ws = (char*)d_ws;
    u16* WtAttn = (u16*)ws; ws += (size_t)3072 * 1024 * 2;
    u16* WtProj = (u16*)ws; ws += (size_t)1024 * 1024 * 2;
    u16* WtFc   = (u16*)ws; ws += (size_t)4096 * 1024 * 2;
    u16* WtFc2  = (u16*)ws; ws += (size_t)1024 * 4096 * 2;
    u16* bufA   = (u16*)ws; ws += (size_t)4096 * 1024 * 2;  // h / y / h2
    u16* bufB   = (u16*)ws; ws += (size_t)4096 * 4096 * 2;  // qkv / m
    float* x1   = (float*)ws; ws += (size_t)4096 * 1024 * 4;
    u16* Vtg    = (u16*)x1;      // alias: x1 not live until proj GEMM; Vt dead by then
    float* P0   = (float*)d_ws;  // FC2 partial: overlays WtAttn+WtProj+WtFc (dead then)

    // fused prep: 4 weight transposes + ln1 (all independent), one launch
    prep_kernel<<<4096, 256, 0, stream>>>(x, ln1_s, ln1_b, bufA,
                                          W_attn, WtAttn, W_proj, WtProj,
                                          W_fc, WtFc, W_fc2, WtFc2);

    // attention branch (QKV GEMM writes Q,K to bufB and V directly to Vtg transposed)
    gemm_qkv_kernel<<<dim3(24, 32), 256, 0, stream>>>(bufA, WtAttn, b_attn, bufB, Vtg);
    attn_kernel<<<dim3(32, NHEAD), 512, 0, stream>>>(bufB, Vtg, bufA);
    gemm_kernel<64, 0, 0, 1, 1><<<dim3(16, 32, 1), 256, 0, stream>>>(
        bufA, 1024, WtProj, 1024, b_proj, x, nullptr, x1, nullptr, 4096, 1024, 1024);

    // MLP branch
    ln_kernel<<<TSEQ / 4, 256, 0, stream>>>(x1, ln2_s, ln2_b, bufA);
    gemm256_kernel<<<dim3(32, 16), 512, 0, stream>>>(
        bufA, WtFc, b_fc, bufB, 4096, 4096, 1024);
    // FC2 split-K=2: z=0 -> P0 partial; z=1 -> out with x1 + b_fc2 fused (FUSE_Z1)
    gemm_kernel<128, 0, 0, 0, 0, 1><<<dim3(8, 32, 2), 256, 0, stream>>>(
        bufB, 4096, WtFc2, 4096, b_fc2, x1, nullptr, P0, out, 4096, 1024, 2048);
    fc2_merge_kernel<<<4096, 256, 0, stream>>>(out, P0);
}

// Round 19
// 260.777 us; speedup vs baseline: 1.3935x; 1.0412x over previous
//
#include <hip/hip_runtime.h>
#include <hip/hip_bf16.h>

typedef short bf16x8 __attribute__((ext_vector_type(8)));
typedef float f32x4 __attribute__((ext_vector_type(4)));
typedef unsigned short u16;
typedef unsigned int u32;

// dims (fixed per problem)
#define TSEQ 4096
#define DMODEL 1024
#define NHEAD 16
#define DHEAD 64
#define DFF 4096

__device__ __forceinline__ u16 f2bf(float f) {
    u32 u = __builtin_bit_cast(u32, f);
    u32 lsb = (u >> 16) & 1u;
    u += 0x7fffu + lsb;
    return (u16)(u >> 16);
}

__device__ __forceinline__ float exp2_hw(float x) {   // 2^x
    float r;
    asm("v_exp_f32 %0, %1" : "=v"(r) : "v"(x));
    return r;
}

__device__ __forceinline__ float rcp_hw(float x) {    // 1/x (approx, ~1ulp)
    float r;
    asm("v_rcp_f32 %0, %1" : "=v"(r) : "v"(x));
    return r;
}

__device__ __forceinline__ u32 cvt_pk_bf16(float a, float b) {  // lo=bf16(a), hi=bf16(b)
    u32 r;
    asm("v_cvt_pk_bf16_f32 %0, %1, %2" : "=v"(r) : "v"(a), "v"(b));
    return r;
}

__device__ __forceinline__ void gload_lds16(const u16* g, u16* l) {
    __builtin_amdgcn_global_load_lds(
        (const __attribute__((address_space(1))) u32*)g,
        (__attribute__((address_space(3))) u32*)l, 16, 0, 0);
}

// T1 XCD swizzle (m157/m204): same-row-panel blocks -> same XCD's L2.
// Requires gridDim.x*gridDim.y % 8 == 0 (all our GEMM grids qualify).
__device__ __forceinline__ void xcd_swizzle(int& bx, int& by) {
    const int gx = gridDim.x;
    const int nwg = gx * gridDim.y;
    const int flat = by * gx + bx;
    const int q = nwg >> 3;
    const int swz = (flat & 7) * q + (flat >> 3);
    bx = swz % gx;
    by = swz / gx;
}

// ---------------- fused prep: 4x weight transpose+cast AND ln1, one launch ----------
__device__ __forceinline__ void transpose_tile(
    const float* __restrict__ W, u16* __restrict__ Wt, int K, int N, int bx, int by,
    float (*tile)[65])
{
    const int t = threadIdx.x;
    const int c = t & 63, r4 = t >> 6;
    const int col0 = bx * 64;  // N dim
    const int row0 = by * 64;  // K dim
#pragma unroll
    for (int p = 0; p < 16; p++) {
        const int r = 4 * p + r4;
        tile[r][c] = W[(size_t)(row0 + r) * N + col0 + c];
    }
    __syncthreads();
#pragma unroll
    for (int p = 0; p < 16; p++) {
        const int r = 4 * p + r4;
        Wt[(size_t)(col0 + r) * K + row0 + c] = f2bf(tile[c][r]);
    }
}

__device__ __forceinline__ void ln_rows(
    const float* __restrict__ x, const float* __restrict__ sc,
    const float* __restrict__ bi, u16* __restrict__ out, int blk)
{
    const int lane = threadIdx.x & 63;
    const int row = blk * 4 + (threadIdx.x >> 6);
    const float* xr = x + (size_t)row * DMODEL;
    float4 v[4];
    float s = 0.f, s2 = 0.f;
#pragma unroll
    for (int q = 0; q < 4; q++) {
        v[q] = *(const float4*)(xr + 4 * (lane + 64 * q));
        s  += v[q].x + v[q].y + v[q].z + v[q].w;
        s2 += v[q].x * v[q].x + v[q].y * v[q].y + v[q].z * v[q].z + v[q].w * v[q].w;
    }
#pragma unroll
    for (int off = 1; off < 64; off <<= 1) {
        s  += __shfl_xor(s, off);
        s2 += __shfl_xor(s2, off);
    }
    const float mu = s * (1.f / DMODEL);
    const float rstd = rsqrtf(s2 * (1.f / DMODEL) - mu * mu + 1e-5f);
#pragma unroll
    for (int q = 0; q < 4; q++) {
        const int c = 4 * (lane + 64 * q);
        const float4 scv = *(const float4*)(sc + c);
        const float4 biv = *(const float4*)(bi + c);
        ushort4 ov;
        ov.x = f2bf((v[q].x - mu) * rstd * scv.x + biv.x);
        ov.y = f2bf((v[q].y - mu) * rstd * scv.y + biv.y);
        ov.z = f2bf((v[q].z - mu) * rstd * scv.z + biv.z);
        ov.w = f2bf((v[q].w - mu) * rstd * scv.w + biv.w);
        *(ushort4*)(out + (size_t)row * DMODEL + c) = ov;
    }
}

__global__ __launch_bounds__(256)
void prep_kernel(const float* __restrict__ x, const float* __restrict__ ln1_s,
                 const float* __restrict__ ln1_b, u16* __restrict__ h,
                 const float* __restrict__ W_attn, u16* __restrict__ WtAttn,
                 const float* __restrict__ W_proj, u16* __restrict__ WtProj,
                 const float* __restrict__ W_fc,   u16* __restrict__ WtFc,
                 const float* __restrict__ W_fc2,  u16* __restrict__ WtFc2)
{
    __shared__ float tile[64][65];
    int b = blockIdx.x;
    if (b < 1024) { ln_rows(x, ln1_s, ln1_b, h, b); return; }
    b -= 1024;
    if (b < 768)  { transpose_tile(W_attn, WtAttn, 1024, 3072, b % 48, b / 48, tile); return; }
    b -= 768;
    if (b < 256)  { transpose_tile(W_proj, WtProj, 1024, 1024, b % 16, b / 16, tile); return; }
    b -= 256;
    if (b < 1024) { transpose_tile(W_fc,   WtFc,   1024, 4096, b % 64, b / 64, tile); return; }
    b -= 1024;
    transpose_tile(W_fc2, WtFc2, 4096, 1024, b % 16, b / 16, tile);
}

// ---------------- layernorm: f32 [T,1024] -> bf16 [T,1024] ----------------
__global__ __launch_bounds__(256)
void ln_kernel(const float* __restrict__ x, const float* __restrict__ sc,
               const float* __restrict__ bi, u16* __restrict__ out)
{
    ln_rows(x, sc, bi, out, blockIdx.x);
}

// ---------------- QKV GEMM with fused V-transpose, 2-phase dbuf staging -------------
// C[4096,3072] = h * WtAttn^T + b_attn. Q,K tiles -> qkv[T,3072]; V tiles (n0>=2048)
// write DIRECTLY to Vt[h*64+d][T] (packed 8B per (i,j)). Double-buffered K-loop
// (attn-proven, R10): one barrier per K-step, next tile's global_load_lds in flight
// during compute. LDS 64KB -> 2 blocks/CU.
__global__ __launch_bounds__(256)
void gemm_qkv_kernel(const u16* __restrict__ A, const u16* __restrict__ Bt,
                     const float* __restrict__ bias, u16* __restrict__ outb,
                     u16* __restrict__ Vt)
{
    constexpr int K = 1024, N = 3072;
    __shared__ u16 Alds[2][128 * 64];
    __shared__ u16 Blds[2][128 * 64];
    const int t = threadIdx.x;
    const int lane = t & 63, w = t >> 6;
    const int g = lane >> 4, fr = lane & 15;
    int bx = blockIdx.x, by = blockIdx.y;
    xcd_swizzle(bx, by);                       // T1: L2 locality
    const int m0 = by * 128, n0 = bx * 128;
    const int rowbase = (w >> 1) * 64;
    const int colbase = (w & 1) * 64;

    f32x4 zero4 = {0.f, 0.f, 0.f, 0.f};
    f32x4 acc[4][4];
#pragma unroll
    for (int i = 0; i < 4; i++)
#pragma unroll
        for (int j = 0; j < 4; j++) acc[i][j] = zero4;

#define QKV_STAGE(buf, kk) do { \
        for (int p = 0; p < 4; p++) { \
            const int c = p * 256 + t; \
            const int r = c >> 3, j = (c & 7) ^ (r & 7); \
            gload_lds16(A + (size_t)(m0 + r) * K + (kk) + j * 8, Alds[buf] + c * 8); \
        } \
        for (int p = 0; p < 4; p++) { \
            const int c = p * 256 + t; \
            const int r = c >> 3, j = (c & 7) ^ (r & 7); \
            gload_lds16(Bt + (size_t)(n0 + r) * K + (kk) + j * 8, Blds[buf] + c * 8); \
        } } while (0)

    QKV_STAGE(0, 0);
    int cur = 0;
    for (int k0 = 0; k0 < K; k0 += 64) {
        __syncthreads();    // drains stage of buf[cur]; readers done with buf[cur^1]
        if (k0 + 64 < K) QKV_STAGE(cur ^ 1, k0 + 64);
#pragma unroll
        for (int ks = 0; ks < 2; ks++) {
            bf16x8 af[4], bfr[4];
#pragma unroll
            for (int i = 0; i < 4; i++)
                af[i] = *(const bf16x8*)(Alds[cur] + (rowbase + i * 16 + fr) * 64 + (((ks * 4 + g) ^ (fr & 7)) * 8));
#pragma unroll
            for (int j = 0; j < 4; j++)
                bfr[j] = *(const bf16x8*)(Blds[cur] + (colbase + j * 16 + fr) * 64 + (((ks * 4 + g) ^ (fr & 7)) * 8));
#pragma unroll
            for (int i = 0; i < 4; i++)
#pragma unroll
                for (int j = 0; j < 4; j++)
                    acc[i][j] = __builtin_amdgcn_mfma_f32_16x16x32_bf16(af[i], bfr[j], acc[i][j], 0, 0, 0);
        }
        cur ^= 1;
    }
#undef QKV_STAGE

    if (n0 >= 2048) {
        // V tile: write transposed, packed 8B per (i,j)
#pragma unroll
        for (int j = 0; j < 4; j++) {
            const int col = n0 + colbase + j * 16 + fr;
            const float bv = bias[col];
            const int vrow = col - 2048;         // = h*64 + d
#pragma unroll
            for (int i = 0; i < 4; i++) {
                const int trow = m0 + rowbase + i * 16 + g * 4;
                uint2 pk;
                pk.x = cvt_pk_bf16(acc[i][j][0] + bv, acc[i][j][1] + bv);
                pk.y = cvt_pk_bf16(acc[i][j][2] + bv, acc[i][j][3] + bv);
                *(uint2*)(Vt + (size_t)vrow * TSEQ + trow) = pk;
            }
        }
    } else {
#pragma unroll
        for (int j = 0; j < 4; j++) {
            const int col = n0 + colbase + j * 16 + fr;
            const float bv = bias[col];
#pragma unroll
            for (int i = 0; i < 4; i++) {
#pragma unroll
                for (int r = 0; r < 4; r++) {
                    const int row = m0 + rowbase + i * 16 + g * 4 + r;
                    outb[(size_t)row * N + col] = f2bf(acc[i][j][r] + bv);
                }
            }
        }
    }
}

// ---------------- GEMM: C[M,N] = A[M,K](bf16) * Bt[N,K](bf16)^T [+bias][+gelu][+res] --
// BM=128, BK=64, XOR-swizzled LDS (T2/m173), 2-phase double-buffered staging
// (attn-proven): one barrier per K-step. Split-K via gridDim.z; FUSE_Z1: z==1
// partial additionally adds res + bias (final merge only adds the z0 part).
template<int BN, int GELU_F, int OUT_BF16, int HAS_RES, int HAS_BIAS, int FUSE_Z1 = 0>
__global__ __launch_bounds__(256)
void gemm_kernel(const u16* __restrict__ A, int lda,
                 const u16* __restrict__ Bt, int ldb,
                 const float* __restrict__ bias, const float* __restrict__ res,
                 u16* __restrict__ outb, float* __restrict__ outf0,
                 float* __restrict__ outf1, int M, int N, int Kblk)
{
    constexpr int MI = (BN == 128) ? 4 : 2;
    __shared__ u16 Alds[2][128 * 64];
    __shared__ u16 Blds[2][BN * 64];
    const int t = threadIdx.x;
    const int lane = t & 63, w = t >> 6;
    const int g = lane >> 4, fr = lane & 15;
    int bx = blockIdx.x, by = blockIdx.y;
    xcd_swizzle(bx, by);                       // T1: L2 locality
    const int m0 = by * 128, n0 = bx * BN;
    const size_t koff = (size_t)blockIdx.z * Kblk;
    const int rowbase = (BN == 128) ? (w >> 1) * 64 : w * 32;
    const int colbase = (BN == 128) ? (w & 1) * 64 : 0;
    float* outf = blockIdx.z ? outf1 : outf0;

    f32x4 zero4 = {0.f, 0.f, 0.f, 0.f};
    f32x4 acc[MI][4];
#pragma unroll
    for (int i = 0; i < MI; i++)
#pragma unroll
        for (int j = 0; j < 4; j++) acc[i][j] = zero4;

#define G_STAGE(buf, kk) do { \
        for (int p = 0; p < 4; p++) { \
            const int c = p * 256 + t; \
            const int r = c >> 3, j = (c & 7) ^ (r & 7); \
            gload_lds16(A + (size_t)(m0 + r) * lda + koff + (kk) + j * 8, Alds[buf] + c * 8); \
        } \
        for (int p = 0; p < (BN == 128 ? 4 : 2); p++) { \
            const int c = p * 256 + t; \
            const int r = c >> 3, j = (c & 7) ^ (r & 7); \
            gload_lds16(Bt + (size_t)(n0 + r) * ldb + koff + (kk) + j * 8, Blds[buf] + c * 8); \
        } } while (0)

    G_STAGE(0, 0);
    int cur = 0;
    for (int k0 = 0; k0 < Kblk; k0 += 64) {
        __syncthreads();    // drains stage of buf[cur]; readers done with buf[cur^1]
        if (k0 + 64 < Kblk) G_STAGE(cur ^ 1, k0 + 64);
#pragma unroll
        for (int ks = 0; ks < 2; ks++) {
            bf16x8 af[MI], bfr[4];
#pragma unroll
            for (int i = 0; i < MI; i++)
                af[i] = *(const bf16x8*)(Alds[cur] + (rowbase + i * 16 + fr) * 64 + (((ks * 4 + g) ^ (fr & 7)) * 8));
#pragma unroll
            for (int j = 0; j < 4; j++)
                bfr[j] = *(const bf16x8*)(Blds[cur] + (colbase + j * 16 + fr) * 64 + (((ks * 4 + g) ^ (fr & 7)) * 8));
#pragma unroll
            for (int i = 0; i < MI; i++)
#pragma unroll
                for (int j = 0; j < 4; j++)
                    acc[i][j] = __builtin_amdgcn_mfma_f32_16x16x32_bf16(af[i], bfr[j], acc[i][j], 0, 0, 0);
        }
        cur ^= 1;
    }
#undef G_STAGE

    const bool fuse = FUSE_Z1 && (blockIdx.z == 1);
#pragma unroll
    for (int j = 0; j < 4; j++) {
        const int col = n0 + colbase + j * 16 + fr;
        float bv = 0.f;
        if (HAS_BIAS) bv = bias[col];
        if (FUSE_Z1 && fuse) bv = bias[col];
#pragma unroll
        for (int i = 0; i < MI; i++) {
#pragma unroll
            for (int r = 0; r < 4; r++) {
                const int row = m0 + rowbase + i * 16 + g * 4 + r;
                float v = acc[i][j][r] + bv;
                if (GELU_F) {
                    const float q = 0.7978845608028654f * (v + 0.044715f * v * v * v);
                    const float e = exp2_hw(fminf(q, 30.f) * 2.8853900817779268f);
                    v = v * e * rcp_hw(e + 1.0f);
                }
                if (HAS_RES) v += res[(size_t)row * N + col];
                if (FUSE_Z1 && fuse) v += res[(size_t)row * N + col];
                if (OUT_BF16) outb[(size_t)row * N + col] = f2bf(v);
                else          outf[(size_t)row * N + col] = v;
            }
        }
    }
}

// ---------------- GEMM 256x128 (8 waves): C = A*Bt^T + bias, gelu, bf16 out ---------
// Single-buffered (dbuf would be 96KB -> 1 block/CU; keep 2 blocks/CU).
__global__ __launch_bounds__(512, 2)
void gemm256_kernel(const u16* __restrict__ A, const u16* __restrict__ Bt,
                    const float* __restrict__ bias, u16* __restrict__ outb,
                    int M, int N, int K)
{
    __shared__ u16 Alds[256 * 64];   // 32KB
    __shared__ u16 Blds[128 * 64];   // 16KB
    const int t = threadIdx.x;
    const int lane = t & 63, w = t >> 6;
    const int g = lane >> 4, fr = lane & 15;
    int bx = blockIdx.x, by = blockIdx.y;
    xcd_swizzle(bx, by);                       // T1: L2 locality
    const int m0 = by * 256, n0 = bx * 128;
    const int rowbase = (w >> 1) * 64;
    const int colbase = (w & 1) * 64;

    f32x4 zero4 = {0.f, 0.f, 0.f, 0.f};
    f32x4 acc[4][4];
#pragma unroll
    for (int i = 0; i < 4; i++)
#pragma unroll
        for (int j = 0; j < 4; j++) acc[i][j] = zero4;

    for (int k0 = 0; k0 < K; k0 += 64) {
        __syncthreads();
#pragma unroll
        for (int p = 0; p < 4; p++) {            // A tile: 256x64 = 2048 chunks
            const int c = p * 512 + t;
            const int r = c >> 3, j = (c & 7) ^ (r & 7);
            gload_lds16(A + (size_t)(m0 + r) * K + k0 + j * 8, Alds + c * 8);
        }
#pragma unroll
        for (int p = 0; p < 2; p++) {            // B tile: 128x64 = 1024 chunks
            const int c = p * 512 + t;
            const int r = c >> 3, j = (c & 7) ^ (r & 7);
            gload_lds16(Bt + (size_t)(n0 + r) * K + k0 + j * 8, Blds + c * 8);
        }
        __syncthreads();

#pragma unroll
        for (int ks = 0; ks < 2; ks++) {
            bf16x8 af[4], bfr[4];
#pragma unroll
            for (int i = 0; i < 4; i++)
                af[i] = *(const bf16x8*)(Alds + (rowbase + i * 16 + fr) * 64 + (((ks * 4 + g) ^ (fr & 7)) * 8));
#pragma unroll
            for (int j = 0; j < 4; j++)
                bfr[j] = *(const bf16x8*)(Blds + (colbase + j * 16 + fr) * 64 + (((ks * 4 + g) ^ (fr & 7)) * 8));
#pragma unroll
            for (int i = 0; i < 4; i++)
#pragma unroll
                for (int j = 0; j < 4; j++)
                    acc[i][j] = __builtin_amdgcn_mfma_f32_16x16x32_bf16(af[i], bfr[j], acc[i][j], 0, 0, 0);
        }
    }

#pragma unroll
    for (int j = 0; j < 4; j++) {
        const int col = n0 + colbase + j * 16 + fr;
        const float bv = bias[col];
#pragma unroll
        for (int i = 0; i < 4; i++) {
#pragma unroll
            for (int r = 0; r < 4; r++) {
                const int row = m0 + rowbase + i * 16 + g * 4 + r;
                float v = acc[i][j][r] + bv;
                const float q = 0.7978845608028654f * (v + 0.044715f * v * v * v);
                const float e = exp2_hw(fminf(q, 30.f) * 2.8853900817779268f);
                v = v * e * rcp_hw(e + 1.0f);
                outb[(size_t)row * N + col] = f2bf(v);
            }
        }
    }
}

// ---------------- FC2 merge: out += part(z0) ----------------------------------------
__global__ __launch_bounds__(256)
void fc2_merge_kernel(float* __restrict__ out, const float* __restrict__ part)
{
    const int i = blockIdx.x * 256 + threadIdx.x;
    const float4 o = ((const float4*)out)[i];
    const float4 p = ((const float4*)part)[i];
    float4 v;
    v.x = o.x + p.x;
    v.y = o.y + p.y;
    v.z = o.z + p.z;
    v.w = o.w + p.w;
    ((float4*)out)[i] = v;
}

// -------- attn helper: in-lane online softmax (raw S units) + P pack/write ----------
// p = exp(0.125*(s - m)) = 2^(s*C - m*C), C = 0.125*log2(e). Defer-max: keep old m
// while vm <= m + 64 (== 8 scaled); skip O-rescale when all rows deferred.
// FROZEN (R14/R16 lessons): masking stays inline, no setprio, bounds (512,4).
// Any change that grows VGPR past 64 either spills (R14, at cap 64) or halves
// resident waves (R16, VGPR 112 at cap 128): both ~2-7x slowdowns.
__device__ __forceinline__ void softmax_update(
    const f32x4 st[4], bool diag, int klim, int g, int fr,
    float& mrow, float& lrow, f32x4 o[4], u16* Pl)
{
    const float ninf = -__builtin_inff();
    const float C = 0.125f * 1.4426950408889634f;
    float av[4][4];
#pragma unroll
    for (int ct = 0; ct < 4; ct++)
#pragma unroll
        for (int r = 0; r < 4; r++) {
            float aa = st[ct][r];
            if (diag && (ct * 16 + g * 4 + r) > klim) aa = ninf;
            av[ct][r] = aa;
        }
    float m0 = fmaxf(fmaxf(av[0][0], av[0][1]), fmaxf(av[0][2], av[0][3]));
    float m1 = fmaxf(fmaxf(av[1][0], av[1][1]), fmaxf(av[1][2], av[1][3]));
    float m2 = fmaxf(fmaxf(av[2][0], av[2][1]), fmaxf(av[2][2], av[2][3]));
    float m3 = fmaxf(fmaxf(av[3][0], av[3][1]), fmaxf(av[3][2], av[3][3]));
    float vm = fmaxf(fmaxf(m0, m1), fmaxf(m2, m3));
    vm = fmaxf(vm, __shfl_xor(vm, 16));
    vm = fmaxf(vm, __shfl_xor(vm, 32));
    const float mn = (vm <= mrow + 64.f) ? mrow : vm;   // defer-max (T13)
    const float mnC = mn * C;
    float rs = 0.f;
#pragma unroll
    for (int ct = 0; ct < 4; ct++) {
        const float p0 = exp2_hw(__builtin_fmaf(av[ct][0], C, -mnC));
        const float p1 = exp2_hw(__builtin_fmaf(av[ct][1], C, -mnC));
        const float p2 = exp2_hw(__builtin_fmaf(av[ct][2], C, -mnC));
        const float p3 = exp2_hw(__builtin_fmaf(av[ct][3], C, -mnC));
        rs += (p0 + p1) + (p2 + p3);
        uint2 pk;
        pk.x = cvt_pk_bf16(p0, p1);
        pk.y = cvt_pk_bf16(p2, p3);
        const int chunk = ct * 2 + (g >> 1);
        const int addr = fr * 64 + ((chunk ^ (fr & 7)) * 8) + (g & 1) * 4;
        *(uint2*)(Pl + addr) = pk;
    }
    rs += __shfl_xor(rs, 16);
    rs += __shfl_xor(rs, 32);
    const float sc = exp2_hw((mrow - mn) * C);          // ==1 when deferred
    lrow = __builtin_fmaf(lrow, sc, rs);
    const bool nores = (mn == mrow);
    mrow = mn;
    if (!__all(nores)) {
        float scb[4];
#pragma unroll
        for (int j = 0; j < 4; j++) scb[j] = __shfl(sc, g * 4 + j);
#pragma unroll
        for (int dt = 0; dt < 4; dt++)
#pragma unroll
            for (int j = 0; j < 4; j++) o[dt][j] *= scb[j];
    }
}

// ---------------- causal flash attention, paired q-tiles + split-K, 8 waves --------
// EXACTLY the R12 body (89.4us, VGPR 64, no spill). FROZEN — see softmax_update note.
__global__ __launch_bounds__(512, 4)
void attn_kernel(const u16* __restrict__ qkv, const u16* __restrict__ Vtg,
                 u16* __restrict__ y)
{
    __shared__ u16 Klds[2][128 * 64];   // [k=128][d=64]
    __shared__ u16 Vlds[2][64 * 128];   // [d=64][k=128]
    __shared__ u16 Plds[8][16 * 64];
    const int t = threadIdx.x, lane = t & 63, w = t >> 6;
    const int g = lane >> 4, fr = lane & 15;
    const int wv = w & 3, grp = w >> 2;
    const int hh = blockIdx.y;
    const int ii = blockIdx.x;                 // pair (ii, 63-ii)
    const int ntB = 64 - ii;
    const int qAw = ii * 64 + wv * 16;
    const int qBw = (63 - ii) * 64 + wv * 16;

    // Q fragments: lane (g,fr) holds Q[qw+fr][d = ds*32 + g*8 + i]
    bf16x8 aqA[2], aqB[2];
#pragma unroll
    for (int s = 0; s < 2; s++) {
        aqA[s] = *(const bf16x8*)(qkv + (size_t)(qAw + fr) * 3072 + hh * 64 + s * 32 + g * 8);
        aqB[s] = *(const bf16x8*)(qkv + (size_t)(qBw + fr) * 3072 + hh * 64 + s * 32 + g * 8);
    }

    f32x4 zero4 = {0.f, 0.f, 0.f, 0.f};
    f32x4 oA[4] = {zero4, zero4, zero4, zero4};
    f32x4 oB[4] = {zero4, zero4, zero4, zero4};
    const float ninf = -__builtin_inff();
    float mA = ninf, lA = 0.f, mB = ninf, lB = 0.f;

    // staging: K tile [k=128][d=64] as 1024 chunks [r=c>>3][j], V tile [d=64][k=128]
    // as 1024 chunks [d=c>>4][cj]; dest linear, src XOR-swizzled (grp-half bit kept).
    const int cK0 = t, cK1 = t + 512;
    const int rK0 = cK0 >> 3, jK0 = (cK0 & 7) ^ (rK0 & 7);
    const int rK1 = cK1 >> 3, jK1 = (cK1 & 7) ^ (rK1 & 7);
    const int rv0 = cK0 >> 4, cj0 = cK0 & 15;
    const int jv0 = (cj0 & 8) | ((cj0 & 7) ^ (rv0 & 7));
    const int rv1 = cK1 >> 4, cj1 = cK1 & 15;
    const int jv1 = (cj1 & 8) | ((cj1 & 7) ^ (rv1 & 7));
    const u16* gk0 = qkv + (size_t)rK0 * 3072 + 1024 + hh * 64 + jK0 * 8;
    const u16* gk1 = qkv + (size_t)rK1 * 3072 + 1024 + hh * 64 + jK1 * 8;
    const u16* gv0 = Vtg + (size_t)(hh * 64 + rv0) * TSEQ + jv0 * 8;
    const u16* gv1 = Vtg + (size_t)(hh * 64 + rv1) * TSEQ + jv1 * 8;

#define STAGE(buf, k0) do { \
        gload_lds16(gk0 + (size_t)(k0) * 3072, Klds[buf] + cK0 * 8); \
        gload_lds16(gk1 + (size_t)(k0) * 3072, Klds[buf] + cK1 * 8); \
        gload_lds16(gv0 + (k0), Vlds[buf] + cK0 * 8); \
        gload_lds16(gv1 + (k0), Vlds[buf] + cK1 * 8); \
    } while (0)

    const int nIter = (65 - ii) >> 1;
    STAGE(0, 0);

    int cur = 0;
    for (int j = 0; j < nIter; j++) {
        __syncthreads();   // drains stage(j); all waves done reading buf[cur^1]
        if (j + 1 < nIter) STAGE(cur ^ 1, (j + 1) * 128);

        const int kt = 2 * j + grp;
        const bool aB = kt < ntB;
        const bool aA = kt <= ii;
        if (aB | aA) {
            const u16* Kl = Klds[cur] + grp * (64 * 64);
            const u16* Vl = Vlds[cur];
            const int klim = wv * 16 + fr;

            // S^T frags: st[ct][r] = S[k_local=ct*16+g*4+r][q=qw+fr]
            f32x4 stA[4] = {zero4, zero4, zero4, zero4};
            f32x4 stB[4] = {zero4, zero4, zero4, zero4};
#pragma unroll
            for (int ct = 0; ct < 4; ct++) {
#pragma unroll
                for (int ds = 0; ds < 2; ds++) {
                    const bf16x8 bk = *(const bf16x8*)(Kl + (ct * 16 + fr) * 64 + (((ds * 4 + g) ^ (fr & 7)) * 8));
                    if (aB) stB[ct] = __builtin_amdgcn_mfma_f32_16x16x32_bf16(bk, aqB[ds], stB[ct], 0, 0, 0);
                    if (aA) stA[ct] = __builtin_amdgcn_mfma_f32_16x16x32_bf16(bk, aqA[ds], stA[ct], 0, 0, 0);
                }
            }

            if (aB) {
                softmax_update(stB, kt == ntB - 1, klim, g, fr, mB, lB, oB, Plds[w]);
                __builtin_amdgcn_s_waitcnt(0xc07f);   // lgkmcnt(0): own P writes visible
#pragma unroll
                for (int kkh = 0; kkh < 2; kkh++) {
                    const bf16x8 pa = *(const bf16x8*)(&Plds[w][fr * 64 + (((kkh * 4 + g) ^ (fr & 7)) * 8)]);
#pragma unroll
                    for (int dt = 0; dt < 4; dt++) {
                        const int cc = grp * 8 + kkh * 4 + g;
                        const bf16x8 bv = *(const bf16x8*)(Vl + (dt * 16 + fr) * 128 + (((cc & 8) | ((cc & 7) ^ (fr & 7))) * 8));
                        oB[dt] = __builtin_amdgcn_mfma_f32_16x16x32_bf16(pa, bv, oB[dt], 0, 0, 0);
                    }
                }
            }
            if (aA) {
                softmax_update(stA, kt == ii, klim, g, fr, mA, lA, oA, Plds[w]);
                __builtin_amdgcn_s_waitcnt(0xc07f);
#pragma unroll
                for (int kkh = 0; kkh < 2; kkh++) {
                    const bf16x8 pa = *(const bf16x8*)(&Plds[w][fr * 64 + (((kkh * 4 + g) ^ (fr & 7)) * 8)]);
#pragma unroll
                    for (int dt = 0; dt < 4; dt++) {
                        const int cc = grp * 8 + kkh * 4 + g;
                        const bf16x8 bv = *(const bf16x8*)(Vl + (dt * 16 + fr) * 128 + (((cc & 8) | ((cc & 7) ^ (fr & 7))) * 8));
                        oA[dt] = __builtin_amdgcn_mfma_f32_16x16x32_bf16(pa, bv, oA[dt], 0, 0, 0);
                    }
                }
            }
        }
        cur ^= 1;
    }
#undef STAGE

    // ---- split-K merge: group1 -> LDS, group0 merges + writes ----
    __syncthreads();                      // all staging/compute done; reuse K/V LDS
    float* Of = (float*)&Klds[0][0];      // [wv][s][16q][64d] f32 = 32KB
    float2* Ml = (float2*)&Vlds[0][0];    // [wv][s][16q] {m,l}
    const float C = 0.125f * 1.4426950408889634f;
    if (grp == 1) {
#pragma unroll
        for (int dt = 0; dt < 4; dt++)
#pragma unroll
            for (int jq = 0; jq < 4; jq++) {
                Of[((wv * 2 + 0) * 16 + g * 4 + jq) * 64 + dt * 16 + fr] = oA[dt][jq];
                Of[((wv * 2 + 1) * 16 + g * 4 + jq) * 64 + dt * 16 + fr] = oB[dt][jq];
            }
        if (g == 0) {
            Ml[(wv * 2 + 0) * 16 + fr] = make_float2(mA, lA);
            Ml[(wv * 2 + 1) * 16 + fr] = make_float2(mB, lB);
        }
    }
    __syncthreads();
    if (grp == 0) {
#pragma unroll
        for (int jq = 0; jq < 4; jq++) {
            // tile A
            {
                const float m0 = __shfl(mA, g * 4 + jq), l0 = __shfl(lA, g * 4 + jq);
                const float2 ml1 = Ml[(wv * 2 + 0) * 16 + g * 4 + jq];
                const float mm = fmaxf(m0, ml1.x);
                const float s0 = exp2_hw((m0 - mm) * C);
                const float s1 = exp2_hw((ml1.x - mm) * C);
                const float rl = rcp_hw(__builtin_fmaf(l0, s0, ml1.y * s1));
#pragma unroll
                for (int dt = 0; dt < 4; dt++) {
                    const float o1 = Of[((wv * 2 + 0) * 16 + g * 4 + jq) * 64 + dt * 16 + fr];
                    y[(size_t)(qAw + g * 4 + jq) * DMODEL + hh * 64 + dt * 16 + fr] =
                        f2bf((oA[dt][jq] * s0 + o1 * s1) * rl);
                }
            }
            // tile B
            {
                const float m0 = __shfl(mB, g * 4 + jq), l0 = __shfl(lB, g * 4 + jq);
                const float2 ml1 = Ml[(wv * 2 + 1) * 16 + g * 4 + jq];
                const float mm = fmaxf(m0, ml1.x);
                const float s0 = exp2_hw((m0 - mm) * C);
                const float s1 = exp2_hw((ml1.x - mm) * C);
                const float rl = rcp_hw(__builtin_fmaf(l0, s0, ml1.y * s1));
#pragma unroll
                for (int dt = 0; dt < 4; dt++) {
                    const float o1 = Of[((wv * 2 + 1) * 16 + g * 4 + jq) * 64 + dt * 16 + fr];
                    y[(size_t)(qBw + g * 4 + jq) * DMODEL + hh * 64 + dt * 16 + fr] =
                        f2bf((oB[dt][jq] * s0 + o1 * s1) * rl);
                }
            }
        }
    }
}

extern "C" void kernel_launch(void* const* d_in, const int* in_sizes, int n_in,
                              void* d_out, int out_size, void* d_ws, size_t ws_size,
                              hipStream_t stream)
{
    const float* x      = (const float*)d_in[0];
    const float* ln1_s  = (const float*)d_in[1];
    const float* ln1_b  = (const float*)d_in[2];
    const float* W_attn = (const float*)d_in[3];
    const float* b_attn = (const float*)d_in[4];
    const float* W_proj = (const float*)d_in[5];
    const float* b_proj = (const float*)d_in[6];
    const float* ln2_s  = (const float*)d_in[7];
    const float* ln2_b  = (const float*)d_in[8];
    const float* W_fc   = (const float*)d_in[9];
    const float* b_fc   = (const float*)d_in[10];
    const float* W_fc2  = (const float*)d_in[11];
    const float* b_fc2  = (const float*)d_in[12];
    float* out = (float*)d_out;

    char* ws = (char*)d_ws;
    u16* WtAttn = (u16*)ws; ws += (size_t)3072 * 1024 * 2;
    u16* WtProj = (u16*)ws; ws += (size_t)1024 * 1024 * 2;
    u16* WtFc   = (u16*)ws; ws += (size_t)4096 * 1024 * 2;
    u16* WtFc2  = (u16*)ws; ws += (size_t)1024 * 4096 * 2;
    u16* bufA   = (u16*)ws; ws += (size_t)4096 * 1024 * 2;  // h / y / h2
    u16* bufB   = (u16*)ws; ws += (size_t)4096 * 4096 * 2;  // qkv / m
    float* x1   = (float*)ws; ws += (size_t)4096 * 1024 * 4;
    u16* Vtg    = (u16*)x1;      // alias: x1 not live until proj GEMM; Vt dead by then
    float* P0   = (float*)d_ws;  // FC2 partial: overlays WtAttn+WtProj+WtFc (dead then)

    // fused prep: 4 weight transposes + ln1 (all independent), one launch
    prep_kernel<<<4096, 256, 0, stream>>>(x, ln1_s, ln1_b, bufA,
                                          W_attn, WtAttn, W_proj, WtProj,
                                          W_fc, WtFc, W_fc2, WtFc2);

    // attention branch (QKV GEMM writes Q,K to bufB and V directly to Vtg transposed)
    gemm_qkv_kernel<<<dim3(24, 32), 256, 0, stream>>>(bufA, WtAttn, b_attn, bufB, Vtg);
    attn_kernel<<<dim3(32, NHEAD), 512, 0, stream>>>(bufB, Vtg, bufA);
    gemm_kernel<64, 0, 0, 1, 1><<<dim3(16, 32, 1), 256, 0, stream>>>(
        bufA, 1024, WtProj, 1024, b_proj, x, nullptr, x1, nullptr, 4096, 1024, 1024);

    // MLP branch
    ln_kernel<<<TSEQ / 4, 256, 0, stream>>>(x1, ln2_s, ln2_b, bufA);
    gemm256_kernel<<<dim3(32, 16), 512, 0, stream>>>(
        bufA, WtFc, b_fc, bufB, 4096, 4096, 1024);
    // FC2 split-K=2: z=0 -> P0 partial; z=1 -> out with x1 + b_fc2 fused (FUSE_Z1)
    gemm_kernel<128, 0, 0, 0, 0, 1><<<dim3(8, 32, 2), 256, 0, stream>>>(
        bufB, 4096, WtFc2, 4096, b_fc2, x1, nullptr, P0, out, 4096, 1024, 2048);
    fc2_merge_kernel<<<4096, 256, 0, stream>>>(out, P0);
}